// Round 1
// baseline (4783.546 us; speedup 1.0000x reference)
//
#include <hip/hip_runtime.h>
#include <math.h>

#define NN 50000
#define NE 800000
#define HD 128
#define NL 3
#define NG 64
#define BN_EPS 1e-5f

// ---------------- degree ----------------
__global__ void deg_kernel(const int* __restrict__ dst, float* __restrict__ deg) {
    int e = blockIdx.x * 256 + threadIdx.x;
    if (e < NE) {
        int d = dst[e];
        if ((unsigned)d < NN) atomicAdd(&deg[d], 1.0f);
    }
}

// ---------------- scatter-add of source features ----------------
// thread t -> edge e = t/32, float4 chunk q = t%32
__global__ void scatter_kernel(const float* __restrict__ x, const int* __restrict__ src,
                               const int* __restrict__ dst, float* __restrict__ agg) {
    int t = blockIdx.x * 256 + threadIdx.x;
    int e = t >> 5, q = t & 31;
    if (e < NE) {
        int s = src[e], d = dst[e];
        if ((unsigned)s < NN && (unsigned)d < NN) {
            float4 v = ((const float4*)x)[s * 32 + q];
            float* ap = &agg[d * HD + q * 4];
            atomicAdd(ap + 0, v.x);
            atomicAdd(ap + 1, v.y);
            atomicAdd(ap + 2, v.z);
            atomicAdd(ap + 3, v.w);
        }
    }
}

// ---------------- weight transpose: Wt[k][j], k in [0,256) = [Wl | Wr] ----------------
__global__ void wt_kernel(const float* __restrict__ Wl, const float* __restrict__ Wr,
                          float* __restrict__ Wt) {
    int idx = blockIdx.x * 256 + threadIdx.x;
    if (idx < 256 * HD) {
        int k = idx >> 7, j = idx & 127;
        Wt[idx] = (k < HD) ? Wl[j * HD + k] : Wr[j * HD + (k - HD)];
    }
}

// ---------------- fused GEMM: out = (agg/deg)@Wl^T + bl + hin@Wr^T, ReLU, BN partials ----
// block: 32 nodes x 128 channels, 256 threads, thread tile 4x4
__global__ __launch_bounds__(256)
void gemm_kernel(const float* __restrict__ agg, const float* __restrict__ hin,
                 const float* __restrict__ deg, const float* __restrict__ Wt,
                 const float* __restrict__ bias, float* __restrict__ htmp,
                 float* __restrict__ stats) {
    __shared__ float a_s[32 * 260];   // [node][k], k in [0,256), pad to 260
    __shared__ float w_s[32 * HD];    // [kk][j]
    __shared__ float st_s[2 * HD];    // per-block BN partials
    const int tid = threadIdx.x;
    const int n0 = blockIdx.x * 32;
    st_s[tid] = 0.0f;

    // stage A tile: 32 rows x 256 k (agg/deg | hin), as float4
#pragma unroll
    for (int t = 0; t < 8; ++t) {
        int idx = tid + t * 256;          // float4 slot, 2048 total
        int n = idx >> 6, q = idx & 63;   // q: float4 within 256-wide row
        int gn = n0 + n;
        float4 v = make_float4(0.f, 0.f, 0.f, 0.f);
        if (gn < NN) {
            if (q < 32) {
                v = ((const float4*)agg)[gn * 32 + q];
                float dg = deg[gn];
                float r = 1.0f / (dg > 1.0f ? dg : 1.0f);
                v.x *= r; v.y *= r; v.z *= r; v.w *= r;
            } else {
                v = ((const float4*)hin)[gn * 32 + (q - 32)];
            }
        }
        *((float4*)&a_s[n * 260 + q * 4]) = v;
    }

    float acc[4][4];
#pragma unroll
    for (int i = 0; i < 4; ++i)
#pragma unroll
        for (int j = 0; j < 4; ++j) acc[i][j] = 0.0f;

    const int ty = tid >> 5;   // 0..7  (node group: 4 nodes)
    const int tx = tid & 31;   // 0..31 (channel group: 4 channels)

    for (int k0 = 0; k0 < 256; k0 += 32) {
        __syncthreads();
        // stage weight chunk w_s[kk][j] from Wt (coalesced float4)
#pragma unroll
        for (int t = 0; t < 4; ++t) {
            int idx = tid + t * 256;        // float4 slot, 1024 total
            int kk = idx >> 5, qj = idx & 31;
            ((float4*)&w_s[kk * HD])[qj] = ((const float4*)Wt)[(k0 + kk) * 32 + qj];
        }
        __syncthreads();
#pragma unroll
        for (int kk = 0; kk < 32; ++kk) {
            float4 wv = ((const float4*)&w_s[kk * HD])[tx];
            const float* ap = &a_s[(ty * 4) * 260 + k0 + kk];
            float a0 = ap[0], a1 = ap[260], a2 = ap[520], a3 = ap[780];
            acc[0][0] += a0 * wv.x; acc[0][1] += a0 * wv.y; acc[0][2] += a0 * wv.z; acc[0][3] += a0 * wv.w;
            acc[1][0] += a1 * wv.x; acc[1][1] += a1 * wv.y; acc[1][2] += a1 * wv.z; acc[1][3] += a1 * wv.w;
            acc[2][0] += a2 * wv.x; acc[2][1] += a2 * wv.y; acc[2][2] += a2 * wv.z; acc[2][3] += a2 * wv.w;
            acc[3][0] += a3 * wv.x; acc[3][1] += a3 * wv.y; acc[3][2] += a3 * wv.z; acc[3][3] += a3 * wv.w;
        }
    }

    float4 bv = ((const float4*)bias)[tx];
    float s0 = 0.f, s1 = 0.f, s2 = 0.f, s3 = 0.f;
    float q0 = 0.f, q1 = 0.f, q2 = 0.f, q3 = 0.f;
#pragma unroll
    for (int i = 0; i < 4; ++i) {
        int gn = n0 + ty * 4 + i;
        if (gn < NN) {
            float4 y;
            y.x = fmaxf(acc[i][0] + bv.x, 0.0f);
            y.y = fmaxf(acc[i][1] + bv.y, 0.0f);
            y.z = fmaxf(acc[i][2] + bv.z, 0.0f);
            y.w = fmaxf(acc[i][3] + bv.w, 0.0f);
            ((float4*)htmp)[gn * 32 + tx] = y;
            s0 += y.x; s1 += y.y; s2 += y.z; s3 += y.w;
            q0 += y.x * y.x; q1 += y.y * y.y; q2 += y.z * y.z; q3 += y.w * y.w;
        }
    }
    int j = tx * 4;
    atomicAdd(&st_s[j + 0], s0); atomicAdd(&st_s[j + 1], s1);
    atomicAdd(&st_s[j + 2], s2); atomicAdd(&st_s[j + 3], s3);
    atomicAdd(&st_s[HD + j + 0], q0); atomicAdd(&st_s[HD + j + 1], q1);
    atomicAdd(&st_s[HD + j + 2], q2); atomicAdd(&st_s[HD + j + 3], q3);
    __syncthreads();
    atomicAdd(&stats[tid], st_s[tid]);
}

// ---------------- BN prep: scale/shift per channel ----------------
__global__ void bnprep_kernel(float* __restrict__ stats, const float* __restrict__ gamma,
                              const float* __restrict__ beta) {
    int c = threadIdx.x;  // 128
    float invN = 1.0f / (float)NN;
    float mu = stats[c] * invN;
    float var = stats[HD + c] * invN - mu * mu;
    var = var < 0.0f ? 0.0f : var;
    float sc = rsqrtf(var + BN_EPS) * gamma[c];
    stats[2 * HD + c] = sc;
    stats[3 * HD + c] = beta[c] - mu * sc;
}

// ---------------- BN apply ----------------
__global__ void bn_kernel(const float* __restrict__ htmp, const float* __restrict__ stats,
                          float* __restrict__ hout) {
    int idx = blockIdx.x * 256 + threadIdx.x;  // float4 idx
    if (idx < NN * 32) {
        int q = idx & 31;
        float4 y = ((const float4*)htmp)[idx];
        float4 sc = ((const float4*)(stats + 2 * HD))[q];
        float4 sh = ((const float4*)(stats + 3 * HD))[q];
        float4 o;
        o.x = y.x * sc.x + sh.x;
        o.y = y.y * sc.y + sh.y;
        o.z = y.z * sc.z + sh.z;
        o.w = y.w * sc.w + sh.w;
        ((float4*)hout)[idx] = o;
    }
}

// ---------------- pooling: segment_sum over batch ----------------
__global__ void pool_kernel(const float* __restrict__ h, const int* __restrict__ batch,
                            float* __restrict__ pooled) {
    int idx = blockIdx.x * 256 + threadIdx.x;  // float4 idx
    if (idx < NN * 32) {
        int n = idx >> 5, q = idx & 31;
        int g = batch[n];
        if ((unsigned)g < NG) {
            float4 v = ((const float4*)h)[idx];
            float* pp = &pooled[g * HD + q * 4];
            atomicAdd(pp + 0, v.x);
            atomicAdd(pp + 1, v.y);
            atomicAdd(pp + 2, v.z);
            atomicAdd(pp + 3, v.w);
        }
    }
}

// ---------------- head: out[g] = sigmoid(pooled[g] . fcw + fcb) ----------------
__global__ void head_kernel(const float* __restrict__ pooled, const float* __restrict__ fcw,
                            const float* __restrict__ fcb, float* __restrict__ out) {
    __shared__ float red[2];
    int g = blockIdx.x, c = threadIdx.x;  // 128 threads
    float v = pooled[g * HD + c] * fcw[c];
#pragma unroll
    for (int o = 32; o > 0; o >>= 1) v += __shfl_xor(v, o);
    if ((c & 63) == 0) red[c >> 6] = v;
    __syncthreads();
    if (c == 0) {
        float s = red[0] + red[1] + fcb[0];
        out[g] = 1.0f / (1.0f + expf(-s));
    }
}

extern "C" void kernel_launch(void* const* d_in, const int* in_sizes, int n_in,
                              void* d_out, int out_size, void* d_ws, size_t ws_size,
                              hipStream_t stream) {
    const float* x    = (const float*)d_in[0];
    const int*   ei   = (const int*)d_in[1];
    const int*   src  = ei;        // edge_index[0]
    const int*   dst  = ei + NE;   // edge_index[1]
    // d_in[2] = edge_attr (unused by reference)
    const int*   batch = (const int*)d_in[3];
    const float* Wl   = (const float*)d_in[4];
    const float* bl   = (const float*)d_in[5];
    const float* Wr   = (const float*)d_in[6];
    const float* gamma = (const float*)d_in[7];
    const float* beta  = (const float*)d_in[8];
    const float* fcw  = (const float*)d_in[9];
    const float* fcb  = (const float*)d_in[10];
    float* out = (float*)d_out;

    float* ws    = (float*)d_ws;
    float* agg   = ws;
    float* htmp  = ws + (size_t)NN * HD;
    float* hA    = ws + 2 * (size_t)NN * HD;
    float* hB    = ws + 3 * (size_t)NN * HD;
    float* deg   = ws + 4 * (size_t)NN * HD;
    float* stats = deg + NN;           // 4*HD floats: sum | sumsq | scale | shift
    float* Wt    = stats + 4 * HD;     // 256*HD
    float* pooled = Wt + 256 * HD;     // NG*HD

    hipMemsetAsync(deg, 0, NN * sizeof(float), stream);
    hipMemsetAsync(pooled, 0, NG * HD * sizeof(float), stream);
    deg_kernel<<<(NE + 255) / 256, 256, 0, stream>>>(dst, deg);

    const float* hin = x;
    float* houts[3] = {hA, hB, hA};
    for (int l = 0; l < NL; ++l) {
        hipMemsetAsync(agg, 0, (size_t)NN * HD * sizeof(float), stream);
        hipMemsetAsync(stats, 0, 2 * HD * sizeof(float), stream);
        wt_kernel<<<(256 * HD + 255) / 256, 256, 0, stream>>>(Wl + l * HD * HD, Wr + l * HD * HD, Wt);
        scatter_kernel<<<(NE * 32 + 255) / 256, 256, 0, stream>>>(hin, src, dst, agg);
        gemm_kernel<<<(NN + 31) / 32, 256, 0, stream>>>(agg, hin, deg, Wt, bl + l * HD, htmp, stats);
        bnprep_kernel<<<1, HD, 0, stream>>>(stats, gamma + l * HD, beta + l * HD);
        bn_kernel<<<(NN * 32 + 255) / 256, 256, 0, stream>>>(htmp, stats, houts[l]);
        hin = houts[l];
    }
    pool_kernel<<<(NN * 32 + 255) / 256, 256, 0, stream>>>(hA, batch, pooled);
    head_kernel<<<NG, HD, 0, stream>>>(pooled, fcw, fcb, out);
}

// Round 2
// 995.743 us; speedup vs baseline: 4.8040x; 4.8040x over previous
//
#include <hip/hip_runtime.h>
#include <math.h>

#define NN 50000
#define NE 800000
#define HD 128
#define NL 3
#define NG 64
#define BN_EPS 1e-5f

// ---------------- CSR build: degree count ----------------
__global__ void degi_kernel(const int* __restrict__ dst, int* __restrict__ degi) {
    int e = blockIdx.x * 256 + threadIdx.x;
    if (e < NE) {
        int d = dst[e];
        if ((unsigned)d < NN) atomicAdd(&degi[d], 1);
    }
}

// ---------------- CSR build: exclusive scan (single block) ----------------
__global__ void scan_kernel(const int* __restrict__ degi, int* __restrict__ rowptr) {
    __shared__ int sums[256];
    const int tid = threadIdx.x;
    const int CH = (NN + 255) / 256;  // 196
    int start = tid * CH;
    int end = start + CH < NN ? start + CH : NN;
    int s = 0;
    for (int i = start; i < end; ++i) s += degi[i];
    sums[tid] = s;
    __syncthreads();
    if (tid == 0) {
        int acc = 0;
        for (int i = 0; i < 256; ++i) { int t = sums[i]; sums[i] = acc; acc += t; }
    }
    __syncthreads();
    int off = sums[tid];
    for (int i = start; i < end; ++i) { rowptr[i] = off; off += degi[i]; }
    if (tid == 255) rowptr[NN] = off;
}

// ---------------- CSR build: fill perm with src indices ----------------
__global__ void fill_kernel(const int* __restrict__ src, const int* __restrict__ dst,
                            int* __restrict__ cursor, int* __restrict__ perm) {
    int e = blockIdx.x * 256 + threadIdx.x;
    if (e < NE) {
        int d = dst[e];
        if ((unsigned)d < NN) {
            int pos = atomicAdd(&cursor[d], 1);
            perm[pos] = src[e];
        }
    }
}

// ---------------- gather aggregation: agg[n] = mean over row of x[src] ----------------
// thread t: node n = t/32, float4 chunk q = t%32
__global__ __launch_bounds__(256)
void gather_kernel(const float* __restrict__ x, const int* __restrict__ rowptr,
                   const int* __restrict__ perm, float* __restrict__ agg) {
    int t = blockIdx.x * 256 + threadIdx.x;
    int n = t >> 5, q = t & 31;
    if (n >= NN) return;
    int r0 = rowptr[n], r1 = rowptr[n + 1];
    float4 s = make_float4(0.f, 0.f, 0.f, 0.f);
    for (int e = r0; e < r1; ++e) {
        int sn = perm[e];
        float4 v = ((const float4*)x)[sn * 32 + q];
        s.x += v.x; s.y += v.y; s.z += v.z; s.w += v.w;
    }
    float r = 1.0f / fmaxf((float)(r1 - r0), 1.0f);
    s.x *= r; s.y *= r; s.z *= r; s.w *= r;
    ((float4*)agg)[n * 32 + q] = s;
}

// ---------------- weight transpose: Wt[k][j], k in [0,256) = [Wl | Wr] ----------------
__global__ void wt_kernel(const float* __restrict__ Wl, const float* __restrict__ Wr,
                          float* __restrict__ Wt) {
    int idx = blockIdx.x * 256 + threadIdx.x;
    if (idx < 256 * HD) {
        int k = idx >> 7, j = idx & 127;
        Wt[idx] = (k < HD) ? Wl[j * HD + k] : Wr[j * HD + (k - HD)];
    }
}

// ---------------- fused GEMM: out = agg@Wl^T + bl + hin@Wr^T, ReLU, BN partials ----
// block: 32 nodes x 128 channels, 256 threads, thread tile 4x4
// NOTE: htmp may alias agg — each block reads only its own 32 rows (staged to LDS
// before the K-loop) and writes only those same rows afterwards.
__global__ __launch_bounds__(256)
void gemm_kernel(const float* __restrict__ agg, const float* __restrict__ hin,
                 const float* __restrict__ Wt, const float* __restrict__ bias,
                 float* __restrict__ htmp, float* __restrict__ stats) {
    __shared__ float a_s[32 * 260];   // [node][k], k in [0,256), pad to 260
    __shared__ float w_s[32 * HD];    // [kk][j]
    __shared__ float st_s[2 * HD];    // per-block BN partials
    const int tid = threadIdx.x;
    const int n0 = blockIdx.x * 32;
    st_s[tid] = 0.0f;

    // stage A tile: 32 rows x 256 k (agg | hin), as float4
#pragma unroll
    for (int t = 0; t < 8; ++t) {
        int idx = tid + t * 256;          // float4 slot, 2048 total
        int n = idx >> 6, q = idx & 63;   // q: float4 within 256-wide row
        int gn = n0 + n;
        float4 v = make_float4(0.f, 0.f, 0.f, 0.f);
        if (gn < NN) {
            if (q < 32) v = ((const float4*)agg)[gn * 32 + q];
            else        v = ((const float4*)hin)[gn * 32 + (q - 32)];
        }
        *((float4*)&a_s[n * 260 + q * 4]) = v;
    }

    float acc[4][4];
#pragma unroll
    for (int i = 0; i < 4; ++i)
#pragma unroll
        for (int j = 0; j < 4; ++j) acc[i][j] = 0.0f;

    const int ty = tid >> 5;   // 0..7  (node group: 4 nodes)
    const int tx = tid & 31;   // 0..31 (channel group: 4 channels)

    for (int k0 = 0; k0 < 256; k0 += 32) {
        __syncthreads();
        // stage weight chunk w_s[kk][j] from Wt (coalesced float4)
#pragma unroll
        for (int t = 0; t < 4; ++t) {
            int idx = tid + t * 256;        // float4 slot, 1024 total
            int kk = idx >> 5, qj = idx & 31;
            ((float4*)&w_s[kk * HD])[qj] = ((const float4*)Wt)[(k0 + kk) * 32 + qj];
        }
        __syncthreads();
#pragma unroll
        for (int kk = 0; kk < 32; ++kk) {
            float4 wv = ((const float4*)&w_s[kk * HD])[tx];
            const float* ap = &a_s[(ty * 4) * 260 + k0 + kk];
            float a0 = ap[0], a1 = ap[260], a2 = ap[520], a3 = ap[780];
            acc[0][0] += a0 * wv.x; acc[0][1] += a0 * wv.y; acc[0][2] += a0 * wv.z; acc[0][3] += a0 * wv.w;
            acc[1][0] += a1 * wv.x; acc[1][1] += a1 * wv.y; acc[1][2] += a1 * wv.z; acc[1][3] += a1 * wv.w;
            acc[2][0] += a2 * wv.x; acc[2][1] += a2 * wv.y; acc[2][2] += a2 * wv.z; acc[2][3] += a2 * wv.w;
            acc[3][0] += a3 * wv.x; acc[3][1] += a3 * wv.y; acc[3][2] += a3 * wv.z; acc[3][3] += a3 * wv.w;
        }
    }

    float4 bv = ((const float4*)bias)[tx];
    float s0 = 0.f, s1 = 0.f, s2 = 0.f, s3 = 0.f;
    float q0 = 0.f, q1 = 0.f, q2 = 0.f, q3 = 0.f;
#pragma unroll
    for (int i = 0; i < 4; ++i) {
        int gn = n0 + ty * 4 + i;
        if (gn < NN) {
            float4 y;
            y.x = fmaxf(acc[i][0] + bv.x, 0.0f);
            y.y = fmaxf(acc[i][1] + bv.y, 0.0f);
            y.z = fmaxf(acc[i][2] + bv.z, 0.0f);
            y.w = fmaxf(acc[i][3] + bv.w, 0.0f);
            ((float4*)htmp)[gn * 32 + tx] = y;
            s0 += y.x; s1 += y.y; s2 += y.z; s3 += y.w;
            q0 += y.x * y.x; q1 += y.y * y.y; q2 += y.z * y.z; q3 += y.w * y.w;
        }
    }
    int j = tx * 4;
    atomicAdd(&st_s[j + 0], s0); atomicAdd(&st_s[j + 1], s1);
    atomicAdd(&st_s[j + 2], s2); atomicAdd(&st_s[j + 3], s3);
    atomicAdd(&st_s[HD + j + 0], q0); atomicAdd(&st_s[HD + j + 1], q1);
    atomicAdd(&st_s[HD + j + 2], q2); atomicAdd(&st_s[HD + j + 3], q3);
    __syncthreads();
    atomicAdd(&stats[tid], st_s[tid]);
}

// ---------------- BN prep: scale/shift per channel ----------------
__global__ void bnprep_kernel(float* __restrict__ stats, const float* __restrict__ gamma,
                              const float* __restrict__ beta) {
    int c = threadIdx.x;  // 128
    float invN = 1.0f / (float)NN;
    float mu = stats[c] * invN;
    float var = stats[HD + c] * invN - mu * mu;
    var = var < 0.0f ? 0.0f : var;
    float sc = rsqrtf(var + BN_EPS) * gamma[c];
    stats[2 * HD + c] = sc;
    stats[3 * HD + c] = beta[c] - mu * sc;
}

// ---------------- BN apply ----------------
__global__ void bn_kernel(const float* __restrict__ htmp, const float* __restrict__ stats,
                          float* __restrict__ hout) {
    int idx = blockIdx.x * 256 + threadIdx.x;  // float4 idx
    if (idx < NN * 32) {
        int q = idx & 31;
        float4 y = ((const float4*)htmp)[idx];
        float4 sc = ((const float4*)(stats + 2 * HD))[q];
        float4 sh = ((const float4*)(stats + 3 * HD))[q];
        float4 o;
        o.x = y.x * sc.x + sh.x;
        o.y = y.y * sc.y + sh.y;
        o.z = y.z * sc.z + sh.z;
        o.w = y.w * sc.w + sh.w;
        ((float4*)hout)[idx] = o;
    }
}

// ---------------- pooling: segment_sum over batch ----------------
__global__ void pool_kernel(const float* __restrict__ h, const int* __restrict__ batch,
                            float* __restrict__ pooled) {
    int idx = blockIdx.x * 256 + threadIdx.x;  // float4 idx
    if (idx < NN * 32) {
        int n = idx >> 5, q = idx & 31;
        int g = batch[n];
        if ((unsigned)g < NG) {
            float4 v = ((const float4*)h)[idx];
            float* pp = &pooled[g * HD + q * 4];
            atomicAdd(pp + 0, v.x);
            atomicAdd(pp + 1, v.y);
            atomicAdd(pp + 2, v.z);
            atomicAdd(pp + 3, v.w);
        }
    }
}

// ---------------- head: out[g] = sigmoid(pooled[g] . fcw + fcb) ----------------
__global__ void head_kernel(const float* __restrict__ pooled, const float* __restrict__ fcw,
                            const float* __restrict__ fcb, float* __restrict__ out) {
    __shared__ float red[2];
    int g = blockIdx.x, c = threadIdx.x;  // 128 threads
    float v = pooled[g * HD + c] * fcw[c];
#pragma unroll
    for (int o = 32; o > 0; o >>= 1) v += __shfl_xor(v, o);
    if ((c & 63) == 0) red[c >> 6] = v;
    __syncthreads();
    if (c == 0) {
        float s = red[0] + red[1] + fcb[0];
        out[g] = 1.0f / (1.0f + expf(-s));
    }
}

extern "C" void kernel_launch(void* const* d_in, const int* in_sizes, int n_in,
                              void* d_out, int out_size, void* d_ws, size_t ws_size,
                              hipStream_t stream) {
    const float* x    = (const float*)d_in[0];
    const int*   ei   = (const int*)d_in[1];
    const int*   src  = ei;        // edge_index[0]
    const int*   dst  = ei + NE;   // edge_index[1]
    // d_in[2] = edge_attr (unused by reference)
    const int*   batch = (const int*)d_in[3];
    const float* Wl   = (const float*)d_in[4];
    const float* bl   = (const float*)d_in[5];
    const float* Wr   = (const float*)d_in[6];
    const float* gamma = (const float*)d_in[7];
    const float* beta  = (const float*)d_in[8];
    const float* fcw  = (const float*)d_in[9];
    const float* fcb  = (const float*)d_in[10];
    float* out = (float*)d_out;

    float* ws    = (float*)d_ws;
    float* agg   = ws;                          // NN*HD, ALSO used as htmp (row-private aliasing)
    float* hA    = ws + (size_t)NN * HD;
    float* hB    = ws + 2 * (size_t)NN * HD;
    float* stats = ws + 3 * (size_t)NN * HD;    // 4*HD: sum | sumsq | scale | shift
    float* Wt    = stats + 4 * HD;              // 256*HD
    float* pooled = Wt + 256 * HD;              // NG*HD
    int*   rowptr = (int*)(pooled + NG * HD);   // NN+1
    int*   cursor = rowptr + NN + 1;            // NN (also used for degree counting)
    int*   perm   = cursor + NN;                // NE

    // ---- CSR build (once per launch; reused by all 3 layers) ----
    hipMemsetAsync(cursor, 0, NN * sizeof(int), stream);
    hipMemsetAsync(pooled, 0, NG * HD * sizeof(float), stream);
    degi_kernel<<<(NE + 255) / 256, 256, 0, stream>>>(dst, cursor);
    scan_kernel<<<1, 256, 0, stream>>>(cursor, rowptr);
    hipMemcpyAsync(cursor, rowptr, NN * sizeof(int), hipMemcpyDeviceToDevice, stream);
    fill_kernel<<<(NE + 255) / 256, 256, 0, stream>>>(src, dst, cursor, perm);

    const float* hin = x;
    float* houts[3] = {hA, hB, hA};
    for (int l = 0; l < NL; ++l) {
        hipMemsetAsync(stats, 0, 2 * HD * sizeof(float), stream);
        wt_kernel<<<(256 * HD + 255) / 256, 256, 0, stream>>>(Wl + l * HD * HD, Wr + l * HD * HD, Wt);
        gather_kernel<<<(NN * 32 + 255) / 256, 256, 0, stream>>>(hin, rowptr, perm, agg);
        gemm_kernel<<<(NN + 31) / 32, 256, 0, stream>>>(agg, hin, Wt, bl + l * HD, agg, stats);
        bnprep_kernel<<<1, HD, 0, stream>>>(stats, gamma + l * HD, beta + l * HD);
        bn_kernel<<<(NN * 32 + 255) / 256, 256, 0, stream>>>(agg, stats, houts[l]);
        hin = houts[l];
    }
    pool_kernel<<<(NN * 32 + 255) / 256, 256, 0, stream>>>(hA, batch, pooled);
    head_kernel<<<NG, HD, 0, stream>>>(pooled, fcw, fcb, out);
}

// Round 3
// 793.524 us; speedup vs baseline: 6.0282x; 1.2548x over previous
//
#include <hip/hip_runtime.h>
#include <math.h>

#define NN 50000
#define NE 800000
#define HD 128
#define NL 3
#define NG 64
#define BN_EPS 1e-5f

// ---------------- CSR build: degree count ----------------
__global__ void degi_kernel(const int* __restrict__ dst, int* __restrict__ degi) {
    int e = blockIdx.x * 256 + threadIdx.x;
    if (e < NE) {
        int d = dst[e];
        if ((unsigned)d < NN) atomicAdd(&degi[d], 1);
    }
}

// ---------------- CSR build: exclusive scan (single block) ----------------
__global__ void scan_kernel(const int* __restrict__ degi, int* __restrict__ rowptr) {
    __shared__ int sums[256];
    const int tid = threadIdx.x;
    const int CH = (NN + 255) / 256;  // 196
    int start = tid * CH;
    int end = start + CH < NN ? start + CH : NN;
    int s = 0;
    for (int i = start; i < end; ++i) s += degi[i];
    sums[tid] = s;
    __syncthreads();
    if (tid == 0) {
        int acc = 0;
        for (int i = 0; i < 256; ++i) { int t = sums[i]; sums[i] = acc; acc += t; }
    }
    __syncthreads();
    int off = sums[tid];
    for (int i = start; i < end; ++i) { rowptr[i] = off; off += degi[i]; }
    if (tid == 255) rowptr[NN] = off;
}

// ---------------- CSR build: fill perm with src indices ----------------
__global__ void fill_kernel(const int* __restrict__ src, const int* __restrict__ dst,
                            int* __restrict__ cursor, int* __restrict__ perm) {
    int e = blockIdx.x * 256 + threadIdx.x;
    if (e < NE) {
        int d = dst[e];
        if ((unsigned)d < NN) {
            int pos = atomicAdd(&cursor[d], 1);
            perm[pos] = src[e];
        }
    }
}

// ---------------- gather aggregation: agg[n] = mean over row of x[src] ----------------
// thread t: node n = t/32, float4 chunk q = t%32
__global__ __launch_bounds__(256)
void gather_kernel(const float* __restrict__ x, const int* __restrict__ rowptr,
                   const int* __restrict__ perm, float* __restrict__ agg) {
    int t = blockIdx.x * 256 + threadIdx.x;
    int n = t >> 5, q = t & 31;
    if (n >= NN) return;
    int r0 = rowptr[n], r1 = rowptr[n + 1];
    float4 s = make_float4(0.f, 0.f, 0.f, 0.f);
    for (int e = r0; e < r1; ++e) {
        int sn = perm[e];
        float4 v = ((const float4*)x)[sn * 32 + q];
        s.x += v.x; s.y += v.y; s.z += v.z; s.w += v.w;
    }
    float r = 1.0f / fmaxf((float)(r1 - r0), 1.0f);
    s.x *= r; s.y *= r; s.z *= r; s.w *= r;
    ((float4*)agg)[n * 32 + q] = s;
}

// ---------------- weight transpose: Wt[k][j], k in [0,256) = [Wl | Wr] ----------------
__global__ void wt_kernel(const float* __restrict__ Wl, const float* __restrict__ Wr,
                          float* __restrict__ Wt) {
    int idx = blockIdx.x * 256 + threadIdx.x;
    if (idx < 256 * HD) {
        int k = idx >> 7, j = idx & 127;
        Wt[idx] = (k < HD) ? Wl[j * HD + k] : Wr[j * HD + (k - HD)];
    }
}

// ---------------- fused GEMM: out = agg@Wl^T + bl + hin@Wr^T, ReLU, BN partials ----
// block: 32 nodes x 128 channels, 256 threads, thread tile 4x4
// NOTE: htmp may alias agg — each block reads only its own 32 rows (staged to LDS
// before the K-loop) and writes only those same rows afterwards.
__global__ __launch_bounds__(256)
void gemm_kernel(const float* __restrict__ agg, const float* __restrict__ hin,
                 const float* __restrict__ Wt, const float* __restrict__ bias,
                 float* __restrict__ htmp, float* __restrict__ stats) {
    __shared__ float a_s[32 * 260];   // [node][k], k in [0,256), pad to 260
    __shared__ float w_s[32 * HD];    // [kk][j]
    __shared__ float st_s[2 * HD];    // per-block BN partials
    const int tid = threadIdx.x;
    const int n0 = blockIdx.x * 32;
    st_s[tid] = 0.0f;

    // stage A tile: 32 rows x 256 k (agg | hin), as float4
#pragma unroll
    for (int t = 0; t < 8; ++t) {
        int idx = tid + t * 256;          // float4 slot, 2048 total
        int n = idx >> 6, q = idx & 63;   // q: float4 within 256-wide row
        int gn = n0 + n;
        float4 v = make_float4(0.f, 0.f, 0.f, 0.f);
        if (gn < NN) {
            if (q < 32) v = ((const float4*)agg)[gn * 32 + q];
            else        v = ((const float4*)hin)[gn * 32 + (q - 32)];
        }
        *((float4*)&a_s[n * 260 + q * 4]) = v;
    }

    float acc[4][4];
#pragma unroll
    for (int i = 0; i < 4; ++i)
#pragma unroll
        for (int j = 0; j < 4; ++j) acc[i][j] = 0.0f;

    const int ty = tid >> 5;   // 0..7  (node group: 4 nodes)
    const int tx = tid & 31;   // 0..31 (channel group: 4 channels)

    for (int k0 = 0; k0 < 256; k0 += 32) {
        __syncthreads();
        // stage weight chunk w_s[kk][j] from Wt (coalesced float4)
#pragma unroll
        for (int t = 0; t < 4; ++t) {
            int idx = tid + t * 256;        // float4 slot, 1024 total
            int kk = idx >> 5, qj = idx & 31;
            ((float4*)&w_s[kk * HD])[qj] = ((const float4*)Wt)[(k0 + kk) * 32 + qj];
        }
        __syncthreads();
#pragma unroll
        for (int kk = 0; kk < 32; ++kk) {
            float4 wv = ((const float4*)&w_s[kk * HD])[tx];
            const float* ap = &a_s[(ty * 4) * 260 + k0 + kk];
            float a0 = ap[0], a1 = ap[260], a2 = ap[520], a3 = ap[780];
            acc[0][0] += a0 * wv.x; acc[0][1] += a0 * wv.y; acc[0][2] += a0 * wv.z; acc[0][3] += a0 * wv.w;
            acc[1][0] += a1 * wv.x; acc[1][1] += a1 * wv.y; acc[1][2] += a1 * wv.z; acc[1][3] += a1 * wv.w;
            acc[2][0] += a2 * wv.x; acc[2][1] += a2 * wv.y; acc[2][2] += a2 * wv.z; acc[2][3] += a2 * wv.w;
            acc[3][0] += a3 * wv.x; acc[3][1] += a3 * wv.y; acc[3][2] += a3 * wv.z; acc[3][3] += a3 * wv.w;
        }
    }

    float4 bv = ((const float4*)bias)[tx];
    float s0 = 0.f, s1 = 0.f, s2 = 0.f, s3 = 0.f;
    float q0 = 0.f, q1 = 0.f, q2 = 0.f, q3 = 0.f;
#pragma unroll
    for (int i = 0; i < 4; ++i) {
        int gn = n0 + ty * 4 + i;
        if (gn < NN) {
            float4 y;
            y.x = fmaxf(acc[i][0] + bv.x, 0.0f);
            y.y = fmaxf(acc[i][1] + bv.y, 0.0f);
            y.z = fmaxf(acc[i][2] + bv.z, 0.0f);
            y.w = fmaxf(acc[i][3] + bv.w, 0.0f);
            ((float4*)htmp)[gn * 32 + tx] = y;
            s0 += y.x; s1 += y.y; s2 += y.z; s3 += y.w;
            q0 += y.x * y.x; q1 += y.y * y.y; q2 += y.z * y.z; q3 += y.w * y.w;
        }
    }
    int j = tx * 4;
    atomicAdd(&st_s[j + 0], s0); atomicAdd(&st_s[j + 1], s1);
    atomicAdd(&st_s[j + 2], s2); atomicAdd(&st_s[j + 3], s3);
    atomicAdd(&st_s[HD + j + 0], q0); atomicAdd(&st_s[HD + j + 1], q1);
    atomicAdd(&st_s[HD + j + 2], q2); atomicAdd(&st_s[HD + j + 3], q3);
    __syncthreads();
    atomicAdd(&stats[tid], st_s[tid]);
}

// ---------------- BN prep: scale/shift per channel ----------------
__global__ void bnprep_kernel(float* __restrict__ stats, const float* __restrict__ gamma,
                              const float* __restrict__ beta) {
    int c = threadIdx.x;  // 128
    float invN = 1.0f / (float)NN;
    float mu = stats[c] * invN;
    float var = stats[HD + c] * invN - mu * mu;
    var = var < 0.0f ? 0.0f : var;
    float sc = rsqrtf(var + BN_EPS) * gamma[c];
    stats[2 * HD + c] = sc;
    stats[3 * HD + c] = beta[c] - mu * sc;
}

// ---------------- BN apply ----------------
__global__ void bn_kernel(const float* __restrict__ htmp, const float* __restrict__ stats,
                          float* __restrict__ hout) {
    int idx = blockIdx.x * 256 + threadIdx.x;  // float4 idx
    if (idx < NN * 32) {
        int q = idx & 31;
        float4 y = ((const float4*)htmp)[idx];
        float4 sc = ((const float4*)(stats + 2 * HD))[q];
        float4 sh = ((const float4*)(stats + 3 * HD))[q];
        float4 o;
        o.x = y.x * sc.x + sh.x;
        o.y = y.y * sc.y + sh.y;
        o.z = y.z * sc.z + sh.z;
        o.w = y.w * sc.w + sh.w;
        ((float4*)hout)[idx] = o;
    }
}

// ---------------- group boundaries from sorted batch: gb[g] = first node of group g ----
__global__ void bounds_kernel(const int* __restrict__ batch, int* __restrict__ gb) {
    int n = blockIdx.x * 256 + threadIdx.x;
    if (n >= NN) return;
    int b = batch[n];
    int bp = (n == 0) ? -1 : batch[n - 1];
    for (int g = bp + 1; g <= b; ++g) gb[g] = n;
    if (n == NN - 1)
        for (int g = b + 1; g <= NG; ++g) gb[g] = NN;
}

// ---------------- pooling: segmented sum (batch sorted), 8 splits per group ----------
__global__ __launch_bounds__(256)
void pool2_kernel(const float* __restrict__ h, const int* __restrict__ gb,
                  float* __restrict__ pooled) {
    __shared__ float red[256 * 4];
    int g = blockIdx.x >> 3, sp = blockIdx.x & 7;
    int s = gb[g], e = gb[g + 1];
    int q = threadIdx.x & 31;   // float4 channel chunk
    int r = threadIdx.x >> 5;   // 0..7 node-parallel row
    float4 a = make_float4(0.f, 0.f, 0.f, 0.f);
    for (int n = s + sp * 8 + r; n < e; n += 64) {
        float4 v = ((const float4*)h)[n * 32 + q];
        a.x += v.x; a.y += v.y; a.z += v.z; a.w += v.w;
    }
    ((float4*)red)[r * 32 + q] = a;
    __syncthreads();
#pragma unroll
    for (int st = 4; st >= 1; st >>= 1) {
        if (r < st) {
            float4 o = ((float4*)red)[(r + st) * 32 + q];
            a.x += o.x; a.y += o.y; a.z += o.z; a.w += o.w;
            ((float4*)red)[r * 32 + q] = a;
        }
        __syncthreads();
    }
    if (r == 0) {
        float* pp = &pooled[g * HD + q * 4];
        atomicAdd(pp + 0, a.x);
        atomicAdd(pp + 1, a.y);
        atomicAdd(pp + 2, a.z);
        atomicAdd(pp + 3, a.w);
    }
}

// ---------------- head: out[g] = sigmoid(pooled[g] . fcw + fcb) ----------------
__global__ void head_kernel(const float* __restrict__ pooled, const float* __restrict__ fcw,
                            const float* __restrict__ fcb, float* __restrict__ out) {
    __shared__ float red[2];
    int g = blockIdx.x, c = threadIdx.x;  // 128 threads
    float v = pooled[g * HD + c] * fcw[c];
#pragma unroll
    for (int o = 32; o > 0; o >>= 1) v += __shfl_xor(v, o);
    if ((c & 63) == 0) red[c >> 6] = v;
    __syncthreads();
    if (c == 0) {
        float s = red[0] + red[1] + fcb[0];
        out[g] = 1.0f / (1.0f + expf(-s));
    }
}

extern "C" void kernel_launch(void* const* d_in, const int* in_sizes, int n_in,
                              void* d_out, int out_size, void* d_ws, size_t ws_size,
                              hipStream_t stream) {
    const float* x    = (const float*)d_in[0];
    const int*   ei   = (const int*)d_in[1];
    const int*   src  = ei;        // edge_index[0]
    const int*   dst  = ei + NE;   // edge_index[1]
    // d_in[2] = edge_attr (unused by reference)
    const int*   batch = (const int*)d_in[3];
    const float* Wl   = (const float*)d_in[4];
    const float* bl   = (const float*)d_in[5];
    const float* Wr   = (const float*)d_in[6];
    const float* gamma = (const float*)d_in[7];
    const float* beta  = (const float*)d_in[8];
    const float* fcw  = (const float*)d_in[9];
    const float* fcb  = (const float*)d_in[10];
    float* out = (float*)d_out;

    float* ws    = (float*)d_ws;
    float* agg   = ws;                          // NN*HD, ALSO used as htmp (row-private aliasing)
    float* hA    = ws + (size_t)NN * HD;
    float* hB    = ws + 2 * (size_t)NN * HD;
    float* stats = ws + 3 * (size_t)NN * HD;    // 4*HD: sum | sumsq | scale | shift
    float* Wt    = stats + 4 * HD;              // 256*HD
    float* pooled = Wt + 256 * HD;              // NG*HD
    int*   rowptr = (int*)(pooled + NG * HD);   // NN+1
    int*   cursor = rowptr + NN + 1;            // NN (also used for degree counting)
    int*   perm   = cursor + NN;                // NE
    int*   gb     = perm + NE;                  // NG+1

    // ---- CSR build (once per launch; reused by all 3 layers) ----
    hipMemsetAsync(cursor, 0, NN * sizeof(int), stream);
    hipMemsetAsync(pooled, 0, NG * HD * sizeof(float), stream);
    degi_kernel<<<(NE + 255) / 256, 256, 0, stream>>>(dst, cursor);
    scan_kernel<<<1, 256, 0, stream>>>(cursor, rowptr);
    hipMemcpyAsync(cursor, rowptr, NN * sizeof(int), hipMemcpyDeviceToDevice, stream);
    fill_kernel<<<(NE + 255) / 256, 256, 0, stream>>>(src, dst, cursor, perm);
    bounds_kernel<<<(NN + 255) / 256, 256, 0, stream>>>(batch, gb);

    const float* hin = x;
    float* houts[3] = {hA, hB, hA};
    for (int l = 0; l < NL; ++l) {
        hipMemsetAsync(stats, 0, 2 * HD * sizeof(float), stream);
        wt_kernel<<<(256 * HD + 255) / 256, 256, 0, stream>>>(Wl + l * HD * HD, Wr + l * HD * HD, Wt);
        gather_kernel<<<(NN * 32 + 255) / 256, 256, 0, stream>>>(hin, rowptr, perm, agg);
        gemm_kernel<<<(NN + 31) / 32, 256, 0, stream>>>(agg, hin, Wt, bl + l * HD, agg, stats);
        bnprep_kernel<<<1, HD, 0, stream>>>(stats, gamma + l * HD, beta + l * HD);
        bn_kernel<<<(NN * 32 + 255) / 256, 256, 0, stream>>>(agg, stats, houts[l]);
        hin = houts[l];
    }
    pool2_kernel<<<NG * 8, 256, 0, stream>>>(hA, gb, pooled);
    head_kernel<<<NG, HD, 0, stream>>>(pooled, fcw, fcb, out);
}

// Round 5
// 726.864 us; speedup vs baseline: 6.5811x; 1.0917x over previous
//
#include <hip/hip_runtime.h>
#include <math.h>

#define NN 50000
#define NE 800000
#define HD 128
#define NL 3
#define NG 64
#define BN_EPS 1e-5f
#define SB 640   // stats slot: sum[128] | sumsq[128] | sc[128] | sh[128] | neg[128]

typedef __attribute__((ext_vector_type(8))) short bf16x8;
typedef __attribute__((ext_vector_type(4))) float f32x4;

__device__ __forceinline__ unsigned short f2bf(float f) {
    unsigned int u = __float_as_uint(f);
    u = (u + 0x7fffu + ((u >> 16) & 1u)) >> 16;
    return (unsigned short)u;
}
__device__ __forceinline__ float bf2f(unsigned short h) {
    return __uint_as_float(((unsigned int)h) << 16);
}

// ---------------- CSR build ----------------
__global__ void degi_kernel(const int* __restrict__ dst, int* __restrict__ degi) {
    int e = blockIdx.x * 256 + threadIdx.x;
    if (e < NE) {
        int d = dst[e];
        if ((unsigned)d < NN) atomicAdd(&degi[d], 1);
    }
}

__global__ void scan_kernel(const int* __restrict__ degi, int* __restrict__ rowptr) {
    __shared__ int sums[256];
    const int tid = threadIdx.x;
    const int CH = (NN + 255) / 256;
    int start = tid * CH;
    int end = start + CH < NN ? start + CH : NN;
    int s = 0;
    for (int i = start; i < end; ++i) s += degi[i];
    sums[tid] = s;
    __syncthreads();
    if (tid == 0) {
        int acc = 0;
        for (int i = 0; i < 256; ++i) { int t = sums[i]; sums[i] = acc; acc += t; }
    }
    __syncthreads();
    int off = sums[tid];
    for (int i = start; i < end; ++i) { rowptr[i] = off; off += degi[i]; }
    if (tid == 255) rowptr[NN] = off;
}

__global__ void fill_kernel(const int* __restrict__ src, const int* __restrict__ dst,
                            int* __restrict__ cursor, int* __restrict__ perm) {
    int e = blockIdx.x * 256 + threadIdx.x;
    if (e < NE) {
        int d = dst[e];
        if ((unsigned)d < NN) {
            int pos = atomicAdd(&cursor[d], 1);
            perm[pos] = src[e];
        }
    }
}

__global__ void bounds_kernel(const int* __restrict__ batch, int* __restrict__ gb) {
    int n = blockIdx.x * 256 + threadIdx.x;
    if (n >= NN) return;
    int b = batch[n];
    int bp = (n == 0) ? -1 : batch[n - 1];
    for (int g = bp + 1; g <= b; ++g) gb[g] = n;
    if (n == NN - 1)
        for (int g = b + 1; g <= NG; ++g) gb[g] = NN;
}

// ---------------- stats slot 0 = identity affine ----------------
__global__ void statsinit_kernel(float* __restrict__ stats0) {
    int c = threadIdx.x;  // 128
    stats0[256 + c] = 1.0f;  // sc
    stats0[384 + c] = 0.0f;  // sh
    stats0[512 + c] = 0.0f;  // neg = -sh/sc
}

// ---- weight prep: W' = W*scp split into bf16 hi/lo planes; bias2 = bl + shp@(Wl+Wr)^T
__global__ void wprep_kernel(const float* __restrict__ Wl, const float* __restrict__ Wr,
                             const float* __restrict__ bl, const float* __restrict__ statsP,
                             unsigned short* __restrict__ Wbh, unsigned short* __restrict__ Wbl,
                             float* __restrict__ bias2) {
    __shared__ float red[256];
    int j = blockIdx.x;   // 0..127 output channel
    int k = threadIdx.x;  // 0..255 contraction index
    float scp = statsP[256 + (k & 127)];
    float shp = statsP[384 + (k & 127)];
    float w = (k < HD) ? Wl[j * HD + k] : Wr[j * HD + (k - HD)];
    float wp = w * scp;
    unsigned short hi = f2bf(wp);
    Wbh[j * 256 + k] = hi;
    Wbl[j * 256 + k] = f2bf(wp - bf2f(hi));
    red[k] = shp * w;
    __syncthreads();
    for (int s = 128; s > 0; s >>= 1) {
        if (k < s) red[k] += red[k + s];
        __syncthreads();
    }
    if (k == 0) bias2[j] = bl[j] + red[0];
}

// ---------------- gather: agg[n] = mean over CSR row of hin[src] (all fp32) ----------
// 32 lanes per node, one float4 chunk per lane
__global__ __launch_bounds__(256)
void gather_kernel(const float* __restrict__ hin, const int* __restrict__ rowptr,
                   const int* __restrict__ perm, const float* __restrict__ statsP,
                   float* __restrict__ agg) {
    int t = blockIdx.x * 256 + threadIdx.x;
    int n = t >> 5, q = t & 31;
    if (n >= NN) return;
    int r0 = rowptr[n], r1 = rowptr[n + 1];
    float4 s = make_float4(0.f, 0.f, 0.f, 0.f);
    for (int e = r0; e < r1; ++e) {
        int sn = perm[e];
        float4 v = ((const float4*)hin)[sn * 32 + q];
        s.x += v.x; s.y += v.y; s.z += v.z; s.w += v.w;
    }
    if (r1 > r0) {
        float r = 1.0f / (float)(r1 - r0);
        s.x *= r; s.y *= r; s.z *= r; s.w *= r;
    } else {
        // deg-0 sentinel: -sh/sc so the BN-folded GEMM contribution is exactly 0
        s = ((const float4*)(statsP + 512))[q];
    }
    ((float4*)agg)[n * 32 + q] = s;
}

// ---------------- split-precision MFMA GEMM ----------------
// y = relu([agg | hin] @ W'^T + bias2)  with W' = [Wl*sc | Wr*sc]
// A fp32 on the fly -> (a_hi + a_lo) bf16; 3 MFMAs per tile: hh + lh + hl.
// block = 256 thr = 4 waves; wave computes 16 rows x 128 cols, K=256.
__global__ __launch_bounds__(256)
void mfma_gemm(const float* __restrict__ agg, const float* __restrict__ hin,
               const unsigned short* __restrict__ Wbh, const unsigned short* __restrict__ Wbl,
               const float* __restrict__ bias2, float* __restrict__ yout,
               float* __restrict__ statsN) {
    __shared__ float ls[64 * 132];
    __shared__ float st[256];
    const int tid = threadIdx.x;
    st[tid] = 0.0f;
    __syncthreads();
    const int wave = tid >> 6, lane = tid & 63;
    const int lm = lane & 15, quad = lane >> 4;
    const int m0 = blockIdx.x * 64 + wave * 16;
    int ar = m0 + lm;
    if (ar >= NN) ar = NN - 1;  // clamp reads; invalid rows zeroed in epilogue

    f32x4 acc[8];
#pragma unroll
    for (int t = 0; t < 8; ++t) acc[t] = (f32x4){0.f, 0.f, 0.f, 0.f};

#pragma unroll
    for (int kc = 0; kc < 8; ++kc) {
        const int k0 = kc * 32;
        const float* Abase = (kc < 4)
            ? (agg + (size_t)ar * HD + k0 + quad * 8)
            : (hin + (size_t)ar * HD + (k0 - 128) + quad * 8);
        float4 v0 = *(const float4*)(Abase);
        float4 v1 = *(const float4*)(Abase + 4);
        float av[8] = {v0.x, v0.y, v0.z, v0.w, v1.x, v1.y, v1.z, v1.w};
        bf16x8 ah, al;
#pragma unroll
        for (int j = 0; j < 8; ++j) {
            unsigned short h = f2bf(av[j]);
            ah[j] = (short)h;
            al[j] = (short)f2bf(av[j] - bf2f(h));
        }
#pragma unroll
        for (int t = 0; t < 8; ++t) {
            const size_t wb = (size_t)(t * 16 + lm) * 256 + k0 + quad * 8;
            bf16x8 bh = *(const bf16x8*)(Wbh + wb);
            bf16x8 bl_ = *(const bf16x8*)(Wbl + wb);
            acc[t] = __builtin_amdgcn_mfma_f32_16x16x32_bf16(ah, bh, acc[t], 0, 0, 0);
            acc[t] = __builtin_amdgcn_mfma_f32_16x16x32_bf16(al, bh, acc[t], 0, 0, 0);
            acc[t] = __builtin_amdgcn_mfma_f32_16x16x32_bf16(ah, bl_, acc[t], 0, 0, 0);
        }
    }

    // epilogue: bias + relu, stash fp32 tile to LDS, BN partial sums
#pragma unroll
    for (int t = 0; t < 8; ++t) {
        int n = t * 16 + lm;
        float bs = bias2[n];
        float s = 0.f, sq = 0.f;
#pragma unroll
        for (int r = 0; r < 4; ++r) {
            int gr = m0 + quad * 4 + r;
            float y = fmaxf(acc[t][r] + bs, 0.f);
            if (gr >= NN) y = 0.f;
            ls[(wave * 16 + quad * 4 + r) * 132 + n] = y;
            s += y; sq += y * y;
        }
        s += __shfl_xor(s, 16); s += __shfl_xor(s, 32);
        sq += __shfl_xor(sq, 16); sq += __shfl_xor(sq, 32);
        if (quad == 0) { atomicAdd(&st[n], s); atomicAdd(&st[128 + n], sq); }
    }
    __syncthreads();
    atomicAdd(&statsN[tid], st[tid]);

    // coalesced fp32 writeback of the 64x128 tile (float4)
#pragma unroll
    for (int it = 0; it < 8; ++it) {
        int slot = tid + it * 256;         // 2048 float4 slots
        int r = slot >> 5, q = slot & 31;
        int g = blockIdx.x * 64 + r;
        if (g < NN) {
            const float* p = &ls[r * 132 + q * 4];
            ((float4*)yout)[(size_t)g * 32 + q] = make_float4(p[0], p[1], p[2], p[3]);
        }
    }
}

// ---------------- BN prep: sc/sh/neg for NEXT layer's folding ----------------
__global__ void bnprep_kernel(float* __restrict__ statsN, const float* __restrict__ gamma,
                              const float* __restrict__ beta) {
    int c = threadIdx.x;  // 128
    float invN = 1.0f / (float)NN;
    float mu = statsN[c] * invN;
    float var = statsN[128 + c] * invN - mu * mu;
    var = var < 0.f ? 0.f : var;
    float sc = rsqrtf(var + BN_EPS) * gamma[c];
    float sh = beta[c] - mu * sc;
    statsN[256 + c] = sc;
    statsN[384 + c] = sh;
    statsN[512 + c] = (sc != 0.f) ? (-sh / sc) : 0.f;
}

// ---------------- pooling: segmented sum of pre-BN y (fp32), batch sorted ----------
__global__ __launch_bounds__(256)
void pool2_kernel(const float* __restrict__ h, const int* __restrict__ gb,
                  float* __restrict__ pooled) {
    __shared__ float red[256 * 4];
    int g = blockIdx.x >> 3, sp = blockIdx.x & 7;
    int s = gb[g], e = gb[g + 1];
    int q = threadIdx.x & 31;
    int r = threadIdx.x >> 5;
    float4 a = make_float4(0.f, 0.f, 0.f, 0.f);
    for (int n = s + sp * 8 + r; n < e; n += 64) {
        float4 v = ((const float4*)h)[n * 32 + q];
        a.x += v.x; a.y += v.y; a.z += v.z; a.w += v.w;
    }
    ((float4*)red)[r * 32 + q] = a;
    __syncthreads();
#pragma unroll
    for (int st = 4; st >= 1; st >>= 1) {
        if (r < st) {
            float4 o = ((float4*)red)[(r + st) * 32 + q];
            a.x += o.x; a.y += o.y; a.z += o.z; a.w += o.w;
            ((float4*)red)[r * 32 + q] = a;
        }
        __syncthreads();
    }
    if (r == 0) {
        float* pp = &pooled[g * HD + q * 4];
        atomicAdd(pp + 0, a.x);
        atomicAdd(pp + 1, a.y);
        atomicAdd(pp + 2, a.z);
        atomicAdd(pp + 3, a.w);
    }
}

// ---------------- head: fold layer-3 BN, dot with fcw, sigmoid ----------------
__global__ void head_kernel(const float* __restrict__ pooled, const int* __restrict__ gb,
                            const float* __restrict__ stats3, const float* __restrict__ fcw,
                            const float* __restrict__ fcb, float* __restrict__ out) {
    __shared__ float red[2];
    int g = blockIdx.x, c = threadIdx.x;  // 128 threads
    float cnt = (float)(gb[g + 1] - gb[g]);
    float v = (pooled[g * HD + c] * stats3[256 + c] + cnt * stats3[384 + c]) * fcw[c];
#pragma unroll
    for (int o = 32; o > 0; o >>= 1) v += __shfl_xor(v, o);
    if ((c & 63) == 0) red[c >> 6] = v;
    __syncthreads();
    if (c == 0) {
        float s = red[0] + red[1] + fcb[0];
        out[g] = 1.0f / (1.0f + expf(-s));
    }
}

extern "C" void kernel_launch(void* const* d_in, const int* in_sizes, int n_in,
                              void* d_out, int out_size, void* d_ws, size_t ws_size,
                              hipStream_t stream) {
    const float* x     = (const float*)d_in[0];
    const int*   ei    = (const int*)d_in[1];
    const int*   src   = ei;
    const int*   dst   = ei + NE;
    const int*   batch = (const int*)d_in[3];
    const float* Wl    = (const float*)d_in[4];
    const float* bl    = (const float*)d_in[5];
    const float* Wr    = (const float*)d_in[6];
    const float* gamma = (const float*)d_in[7];
    const float* beta  = (const float*)d_in[8];
    const float* fcw   = (const float*)d_in[9];
    const float* fcb   = (const float*)d_in[10];
    float* out = (float*)d_out;

    float* ws       = (float*)d_ws;
    float* agg      = ws;                                   // [NN][128] fp32
    float* hA       = agg + (size_t)NN * HD;                // [NN][128]
    float* hB       = hA + (size_t)NN * HD;                 // [NN][128]
    float* bias2    = hB + (size_t)NN * HD;                 // 128
    float* statsAll = bias2 + HD;                           // 4*SB
    float* pooled   = statsAll + 4 * SB;                    // NG*HD
    unsigned short* Wbh = (unsigned short*)(pooled + NG * HD);  // [128][256] bf16
    unsigned short* Wbl = Wbh + 128 * 256;                      // [128][256] bf16
    int* rowptr = (int*)(Wbl + 128 * 256);                  // NN+1
    int* cursor = rowptr + NN + 1;                          // NN
    int* perm   = cursor + NN;                              // NE
    int* gb     = perm + NE;                                // NG+1

    hipMemsetAsync(cursor, 0, NN * sizeof(int), stream);
    hipMemsetAsync(pooled, 0, NG * HD * sizeof(float), stream);
    hipMemsetAsync(statsAll, 0, 4 * SB * sizeof(float), stream);

    degi_kernel<<<(NE + 255) / 256, 256, 0, stream>>>(dst, cursor);
    scan_kernel<<<1, 256, 0, stream>>>(cursor, rowptr);
    hipMemcpyAsync(cursor, rowptr, NN * sizeof(int), hipMemcpyDeviceToDevice, stream);
    fill_kernel<<<(NE + 255) / 256, 256, 0, stream>>>(src, dst, cursor, perm);
    bounds_kernel<<<(NN + 255) / 256, 256, 0, stream>>>(batch, gb);
    statsinit_kernel<<<1, 128, 0, stream>>>(statsAll);

    const float* hin = x;
    float* houts[3] = {hA, hB, hA};
    for (int l = 0; l < NL; ++l) {
        float* stP = statsAll + l * SB;
        float* stN = statsAll + (l + 1) * SB;
        wprep_kernel<<<128, 256, 0, stream>>>(Wl + l * HD * HD, Wr + l * HD * HD,
                                              bl + l * HD, stP, Wbh, Wbl, bias2);
        gather_kernel<<<(NN * 32 + 255) / 256, 256, 0, stream>>>(hin, rowptr, perm, stP, agg);
        mfma_gemm<<<(NN + 63) / 64, 256, 0, stream>>>(agg, hin, Wbh, Wbl, bias2, houts[l], stN);
        bnprep_kernel<<<1, 128, 0, stream>>>(stN, gamma + l * HD, beta + l * HD);
        hin = houts[l];
    }
    pool2_kernel<<<NG * 8, 256, 0, stream>>>(hA, gb, pooled);
    head_kernel<<<NG, 128, 0, stream>>>(pooled, gb, statsAll + 3 * SB, fcw, fcb, out);
}

// Round 6
// 628.671 us; speedup vs baseline: 7.6090x; 1.1562x over previous
//
#include <hip/hip_runtime.h>
#include <math.h>

#define NN 50000
#define NE 800000
#define HD 128
#define NL 3
#define NG 64
#define BN_EPS 1e-5f
#define SB 640   // stats slot: sum[128] | sumsq[128] | sc[128] | sh[128] | neg[128]
#define SCB ((NN + 255) / 256)   // 196 scan blocks

typedef __attribute__((ext_vector_type(8))) short bf16x8;
typedef __attribute__((ext_vector_type(4))) float f32x4;

__device__ __forceinline__ unsigned short f2bf(float f) {
    unsigned int u = __float_as_uint(f);
    u = (u + 0x7fffu + ((u >> 16) & 1u)) >> 16;
    return (unsigned short)u;
}
__device__ __forceinline__ float bf2f(unsigned short h) {
    return __uint_as_float(((unsigned int)h) << 16);
}

// ---------------- CSR build ----------------
__global__ void degi_kernel(const int* __restrict__ dst, int* __restrict__ degi) {
    int e = blockIdx.x * 256 + threadIdx.x;
    if (e < NE) {
        int d = dst[e];
        if ((unsigned)d < NN) atomicAdd(&degi[d], 1);
    }
}

// phase A: per-block sums of degi
__global__ void scanA_kernel(const int* __restrict__ degi, int* __restrict__ bsum) {
    __shared__ int red[256];
    int i = blockIdx.x * 256 + threadIdx.x;
    red[threadIdx.x] = (i < NN) ? degi[i] : 0;
    __syncthreads();
    for (int s = 128; s > 0; s >>= 1) {
        if (threadIdx.x < s) red[threadIdx.x] += red[threadIdx.x + s];
        __syncthreads();
    }
    if (threadIdx.x == 0) bsum[blockIdx.x] = red[0];
}

// phase B: exclusive scan of block sums (196 <= 256, one block)
__global__ void scanB_kernel(int* __restrict__ bsum) {
    __shared__ int sh[256];
    int tid = threadIdx.x;
    int v = (tid < SCB) ? bsum[tid] : 0;
    sh[tid] = v;
    __syncthreads();
    for (int off = 1; off < 256; off <<= 1) {
        int t = (tid >= off) ? sh[tid - off] : 0;
        __syncthreads();
        sh[tid] += t;
        __syncthreads();
    }
    if (tid < SCB) bsum[tid] = sh[tid] - v;  // exclusive
}

// phase C: block-local exclusive scan + block offset -> rowptr
__global__ void scanC_kernel(const int* __restrict__ degi, const int* __restrict__ bsum,
                             int* __restrict__ rowptr) {
    __shared__ int sh[256];
    int tid = threadIdx.x;
    int i = blockIdx.x * 256 + tid;
    int v = (i < NN) ? degi[i] : 0;
    sh[tid] = v;
    __syncthreads();
    for (int off = 1; off < 256; off <<= 1) {
        int t = (tid >= off) ? sh[tid - off] : 0;
        __syncthreads();
        sh[tid] += t;
        __syncthreads();
    }
    int excl = sh[tid] - v + bsum[blockIdx.x];
    if (i < NN) rowptr[i] = excl;
    if (i == NN - 1) rowptr[NN] = excl + v;
}

__global__ void fill_kernel(const int* __restrict__ src, const int* __restrict__ dst,
                            int* __restrict__ cursor, int* __restrict__ perm) {
    int e = blockIdx.x * 256 + threadIdx.x;
    if (e < NE) {
        int d = dst[e];
        if ((unsigned)d < NN) {
            int pos = atomicAdd(&cursor[d], 1);
            perm[pos] = src[e];
        }
    }
}

__global__ void bounds_kernel(const int* __restrict__ batch, int* __restrict__ gb) {
    int n = blockIdx.x * 256 + threadIdx.x;
    if (n >= NN) return;
    int b = batch[n];
    int bp = (n == 0) ? -1 : batch[n - 1];
    for (int g = bp + 1; g <= b; ++g) gb[g] = n;
    if (n == NN - 1)
        for (int g = b + 1; g <= NG; ++g) gb[g] = NN;
}

// ---------------- stats slot 0 = identity affine ----------------
__global__ void statsinit_kernel(float* __restrict__ stats0) {
    int c = threadIdx.x;  // 128
    stats0[256 + c] = 1.0f;  // sc
    stats0[384 + c] = 0.0f;  // sh
    stats0[512 + c] = 0.0f;  // neg = -sh/sc
}

// ---- weight prep: W' = W*scp split into bf16 hi/lo planes; bias2 = bl + shp@(Wl+Wr)^T
__global__ void wprep_kernel(const float* __restrict__ Wl, const float* __restrict__ Wr,
                             const float* __restrict__ bl, const float* __restrict__ statsP,
                             unsigned short* __restrict__ Wbh, unsigned short* __restrict__ Wbl,
                             float* __restrict__ bias2) {
    __shared__ float red[256];
    int j = blockIdx.x;   // 0..127 output channel
    int k = threadIdx.x;  // 0..255 contraction index
    float scp = statsP[256 + (k & 127)];
    float shp = statsP[384 + (k & 127)];
    float w = (k < HD) ? Wl[j * HD + k] : Wr[j * HD + (k - HD)];
    float wp = w * scp;
    unsigned short hi = f2bf(wp);
    Wbh[j * 256 + k] = hi;
    Wbl[j * 256 + k] = f2bf(wp - bf2f(hi));
    red[k] = shp * w;
    __syncthreads();
    for (int s = 128; s > 0; s >>= 1) {
        if (k < s) red[k] += red[k + s];
        __syncthreads();
    }
    if (k == 0) bias2[j] = bl[j] + red[0];
}

// ---------------- gather: agg[n] = mean over CSR row of hin[src] (all fp32) ----------
// 32 lanes per node, one float4 chunk per lane; 4-edge batching for MLP
__global__ __launch_bounds__(256)
void gather_kernel(const float* __restrict__ hin, const int* __restrict__ rowptr,
                   const int* __restrict__ perm, const float* __restrict__ statsP,
                   float* __restrict__ agg) {
    int t = blockIdx.x * 256 + threadIdx.x;
    int n = t >> 5, q = t & 31;
    if (n >= NN) return;
    int r0 = rowptr[n], r1 = rowptr[n + 1];
    float4 s = make_float4(0.f, 0.f, 0.f, 0.f);
    int e = r0;
    for (; e + 4 <= r1; e += 4) {
        int i0 = perm[e], i1 = perm[e + 1], i2 = perm[e + 2], i3 = perm[e + 3];
        float4 v0 = ((const float4*)hin)[i0 * 32 + q];
        float4 v1 = ((const float4*)hin)[i1 * 32 + q];
        float4 v2 = ((const float4*)hin)[i2 * 32 + q];
        float4 v3 = ((const float4*)hin)[i3 * 32 + q];
        s.x += (v0.x + v1.x) + (v2.x + v3.x);
        s.y += (v0.y + v1.y) + (v2.y + v3.y);
        s.z += (v0.z + v1.z) + (v2.z + v3.z);
        s.w += (v0.w + v1.w) + (v2.w + v3.w);
    }
    for (; e < r1; ++e) {
        int sn = perm[e];
        float4 v = ((const float4*)hin)[sn * 32 + q];
        s.x += v.x; s.y += v.y; s.z += v.z; s.w += v.w;
    }
    if (r1 > r0) {
        float r = 1.0f / (float)(r1 - r0);
        s.x *= r; s.y *= r; s.z *= r; s.w *= r;
    } else {
        // deg-0 sentinel: -sh/sc so the BN-folded GEMM contribution is exactly 0
        s = ((const float4*)(statsP + 512))[q];
    }
    ((float4*)agg)[n * 32 + q] = s;
}

// ---------------- split-precision MFMA GEMM ----------------
// y = relu([agg | hin] @ W'^T + bias2)  with W' = [Wl*sc | Wr*sc]
// A fp32 on the fly -> (a_hi + a_lo) bf16; 3 MFMAs per tile: hh + lh + hl.
// block = 256 thr = 4 waves; wave computes 16 rows x 128 cols, K=256.
__global__ __launch_bounds__(256)
void mfma_gemm(const float* __restrict__ agg, const float* __restrict__ hin,
               const unsigned short* __restrict__ Wbh, const unsigned short* __restrict__ Wbl,
               const float* __restrict__ bias2, float* __restrict__ yout,
               float* __restrict__ statsN) {
    __shared__ float ls[64 * 132];
    __shared__ float st[256];
    const int tid = threadIdx.x;
    st[tid] = 0.0f;
    __syncthreads();
    const int wave = tid >> 6, lane = tid & 63;
    const int lm = lane & 15, quad = lane >> 4;
    const int m0 = blockIdx.x * 64 + wave * 16;
    int ar = m0 + lm;
    if (ar >= NN) ar = NN - 1;  // clamp reads; invalid rows zeroed in epilogue

    f32x4 acc[8];
#pragma unroll
    for (int t = 0; t < 8; ++t) acc[t] = (f32x4){0.f, 0.f, 0.f, 0.f};

#pragma unroll
    for (int kc = 0; kc < 8; ++kc) {
        const int k0 = kc * 32;
        const float* Abase = (kc < 4)
            ? (agg + (size_t)ar * HD + k0 + quad * 8)
            : (hin + (size_t)ar * HD + (k0 - 128) + quad * 8);
        float4 v0 = *(const float4*)(Abase);
        float4 v1 = *(const float4*)(Abase + 4);
        float av[8] = {v0.x, v0.y, v0.z, v0.w, v1.x, v1.y, v1.z, v1.w};
        bf16x8 ah, al;
#pragma unroll
        for (int j = 0; j < 8; ++j) {
            unsigned short h = f2bf(av[j]);
            ah[j] = (short)h;
            al[j] = (short)f2bf(av[j] - bf2f(h));
        }
#pragma unroll
        for (int t = 0; t < 8; ++t) {
            const size_t wb = (size_t)(t * 16 + lm) * 256 + k0 + quad * 8;
            bf16x8 bh = *(const bf16x8*)(Wbh + wb);
            bf16x8 bl_ = *(const bf16x8*)(Wbl + wb);
            acc[t] = __builtin_amdgcn_mfma_f32_16x16x32_bf16(ah, bh, acc[t], 0, 0, 0);
            acc[t] = __builtin_amdgcn_mfma_f32_16x16x32_bf16(al, bh, acc[t], 0, 0, 0);
            acc[t] = __builtin_amdgcn_mfma_f32_16x16x32_bf16(ah, bl_, acc[t], 0, 0, 0);
        }
    }

    // epilogue: bias + relu, stash fp32 tile to LDS, BN partial sums
#pragma unroll
    for (int t = 0; t < 8; ++t) {
        int n = t * 16 + lm;
        float bs = bias2[n];
        float s = 0.f, sq = 0.f;
#pragma unroll
        for (int r = 0; r < 4; ++r) {
            int gr = m0 + quad * 4 + r;
            float y = fmaxf(acc[t][r] + bs, 0.f);
            if (gr >= NN) y = 0.f;
            ls[(wave * 16 + quad * 4 + r) * 132 + n] = y;
            s += y; sq += y * y;
        }
        s += __shfl_xor(s, 16); s += __shfl_xor(s, 32);
        sq += __shfl_xor(sq, 16); sq += __shfl_xor(sq, 32);
        if (quad == 0) { atomicAdd(&st[n], s); atomicAdd(&st[128 + n], sq); }
    }
    __syncthreads();
    atomicAdd(&statsN[tid], st[tid]);

    // coalesced fp32 writeback of the 64x128 tile (float4)
#pragma unroll
    for (int it = 0; it < 8; ++it) {
        int slot = tid + it * 256;         // 2048 float4 slots
        int r = slot >> 5, q = slot & 31;
        int g = blockIdx.x * 64 + r;
        if (g < NN) {
            const float* p = &ls[r * 132 + q * 4];
            ((float4*)yout)[(size_t)g * 32 + q] = make_float4(p[0], p[1], p[2], p[3]);
        }
    }
}

// ---------------- BN prep: sc/sh/neg for NEXT layer's folding ----------------
__global__ void bnprep_kernel(float* __restrict__ statsN, const float* __restrict__ gamma,
                              const float* __restrict__ beta) {
    int c = threadIdx.x;  // 128
    float invN = 1.0f / (float)NN;
    float mu = statsN[c] * invN;
    float var = statsN[128 + c] * invN - mu * mu;
    var = var < 0.f ? 0.f : var;
    float sc = rsqrtf(var + BN_EPS) * gamma[c];
    float sh = beta[c] - mu * sc;
    statsN[256 + c] = sc;
    statsN[384 + c] = sh;
    statsN[512 + c] = (sc != 0.f) ? (-sh / sc) : 0.f;
}

// ---------------- pooling: segmented sum of pre-BN y (fp32), batch sorted ----------
__global__ __launch_bounds__(256)
void pool2_kernel(const float* __restrict__ h, const int* __restrict__ gb,
                  float* __restrict__ pooled) {
    __shared__ float red[256 * 4];
    int g = blockIdx.x >> 3, sp = blockIdx.x & 7;
    int s = gb[g], e = gb[g + 1];
    int q = threadIdx.x & 31;
    int r = threadIdx.x >> 5;
    float4 a = make_float4(0.f, 0.f, 0.f, 0.f);
    for (int n = s + sp * 8 + r; n < e; n += 64) {
        float4 v = ((const float4*)h)[n * 32 + q];
        a.x += v.x; a.y += v.y; a.z += v.z; a.w += v.w;
    }
    ((float4*)red)[r * 32 + q] = a;
    __syncthreads();
#pragma unroll
    for (int st = 4; st >= 1; st >>= 1) {
        if (r < st) {
            float4 o = ((float4*)red)[(r + st) * 32 + q];
            a.x += o.x; a.y += o.y; a.z += o.z; a.w += o.w;
            ((float4*)red)[r * 32 + q] = a;
        }
        __syncthreads();
    }
    if (r == 0) {
        float* pp = &pooled[g * HD + q * 4];
        atomicAdd(pp + 0, a.x);
        atomicAdd(pp + 1, a.y);
        atomicAdd(pp + 2, a.z);
        atomicAdd(pp + 3, a.w);
    }
}

// ---------------- head: fold layer-3 BN, dot with fcw, sigmoid ----------------
__global__ void head_kernel(const float* __restrict__ pooled, const int* __restrict__ gb,
                            const float* __restrict__ stats3, const float* __restrict__ fcw,
                            const float* __restrict__ fcb, float* __restrict__ out) {
    __shared__ float red[2];
    int g = blockIdx.x, c = threadIdx.x;  // 128 threads
    float cnt = (float)(gb[g + 1] - gb[g]);
    float v = (pooled[g * HD + c] * stats3[256 + c] + cnt * stats3[384 + c]) * fcw[c];
#pragma unroll
    for (int o = 32; o > 0; o >>= 1) v += __shfl_xor(v, o);
    if ((c & 63) == 0) red[c >> 6] = v;
    __syncthreads();
    if (c == 0) {
        float s = red[0] + red[1] + fcb[0];
        out[g] = 1.0f / (1.0f + expf(-s));
    }
}

extern "C" void kernel_launch(void* const* d_in, const int* in_sizes, int n_in,
                              void* d_out, int out_size, void* d_ws, size_t ws_size,
                              hipStream_t stream) {
    const float* x     = (const float*)d_in[0];
    const int*   ei    = (const int*)d_in[1];
    const int*   src   = ei;
    const int*   dst   = ei + NE;
    const int*   batch = (const int*)d_in[3];
    const float* Wl    = (const float*)d_in[4];
    const float* bl    = (const float*)d_in[5];
    const float* Wr    = (const float*)d_in[6];
    const float* gamma = (const float*)d_in[7];
    const float* beta  = (const float*)d_in[8];
    const float* fcw   = (const float*)d_in[9];
    const float* fcb   = (const float*)d_in[10];
    float* out = (float*)d_out;

    float* ws       = (float*)d_ws;
    float* agg      = ws;                                   // [NN][128] fp32
    float* hA       = agg + (size_t)NN * HD;                // [NN][128]
    float* hB       = hA + (size_t)NN * HD;                 // [NN][128]
    float* bias2    = hB + (size_t)NN * HD;                 // 128
    float* statsAll = bias2 + HD;                           // 4*SB
    float* pooled   = statsAll + 4 * SB;                    // NG*HD
    unsigned short* Wbh = (unsigned short*)(pooled + NG * HD);  // [128][256] bf16
    unsigned short* Wbl = Wbh + 128 * 256;                      // [128][256] bf16
    int* rowptr = (int*)(Wbl + 128 * 256);                  // NN+1
    int* cursor = rowptr + NN + 1;                          // NN (degree counts, then fill cursor)
    int* perm   = cursor + NN;                              // NE
    int* gb     = perm + NE;                                // NG+1
    int* bsum   = gb + NG + 1;                              // SCB

    hipMemsetAsync(cursor, 0, NN * sizeof(int), stream);
    hipMemsetAsync(pooled, 0, NG * HD * sizeof(float), stream);
    hipMemsetAsync(statsAll, 0, 4 * SB * sizeof(float), stream);

    degi_kernel<<<(NE + 255) / 256, 256, 0, stream>>>(dst, cursor);
    scanA_kernel<<<SCB, 256, 0, stream>>>(cursor, bsum);
    scanB_kernel<<<1, 256, 0, stream>>>(bsum);
    scanC_kernel<<<SCB, 256, 0, stream>>>(cursor, bsum, rowptr);
    hipMemcpyAsync(cursor, rowptr, NN * sizeof(int), hipMemcpyDeviceToDevice, stream);
    fill_kernel<<<(NE + 255) / 256, 256, 0, stream>>>(src, dst, cursor, perm);
    bounds_kernel<<<(NN + 255) / 256, 256, 0, stream>>>(batch, gb);
    statsinit_kernel<<<1, 128, 0, stream>>>(statsAll);

    const float* hin = x;
    float* houts[3] = {hA, hB, hA};
    for (int l = 0; l < NL; ++l) {
        float* stP = statsAll + l * SB;
        float* stN = statsAll + (l + 1) * SB;
        wprep_kernel<<<128, 256, 0, stream>>>(Wl + l * HD * HD, Wr + l * HD * HD,
                                              bl + l * HD, stP, Wbh, Wbl, bias2);
        gather_kernel<<<(NN * 32 + 255) / 256, 256, 0, stream>>>(hin, rowptr, perm, stP, agg);
        mfma_gemm<<<(NN + 63) / 64, 256, 0, stream>>>(agg, hin, Wbh, Wbl, bias2, houts[l], stN);
        bnprep_kernel<<<1, 128, 0, stream>>>(stN, gamma + l * HD, beta + l * HD);
        hin = houts[l];
    }
    pool2_kernel<<<NG * 8, 256, 0, stream>>>(hA, gb, pooled);
    head_kernel<<<NG, 128, 0, stream>>>(pooled, gb, statsAll + 3 * SB, fcw, fcb, out);
}

// Round 7
// 615.816 us; speedup vs baseline: 7.7678x; 1.0209x over previous
//
#include <hip/hip_runtime.h>
#include <math.h>

#define NN 50000
#define NE 800000
#define HD 128
#define NL 3
#define NG 64
#define BN_EPS 1e-5f
#define SB 640   // stats slot: sum[128] | sumsq[128] | sc[128] | sh[128] | neg[128]
#define SCB ((NN + 255) / 256)   // 196 scan blocks

typedef __attribute__((ext_vector_type(8))) short bf16x8;
typedef __attribute__((ext_vector_type(4))) float f32x4;

__device__ __forceinline__ unsigned short f2bf(float f) {
    unsigned int u = __float_as_uint(f);
    u = (u + 0x7fffu + ((u >> 16) & 1u)) >> 16;
    return (unsigned short)u;
}
__device__ __forceinline__ float bf2f(unsigned short h) {
    return __uint_as_float(((unsigned int)h) << 16);
}

// ---------------- CSR build ----------------
__global__ void degi_kernel(const int* __restrict__ dst, int* __restrict__ degi) {
    int e = blockIdx.x * 256 + threadIdx.x;
    if (e < NE) {
        int d = dst[e];
        if ((unsigned)d < NN) atomicAdd(&degi[d], 1);
    }
}

// phase A: per-block sums of degi
__global__ void scanA_kernel(const int* __restrict__ degi, int* __restrict__ bsum) {
    __shared__ int red[256];
    int i = blockIdx.x * 256 + threadIdx.x;
    red[threadIdx.x] = (i < NN) ? degi[i] : 0;
    __syncthreads();
    for (int s = 128; s > 0; s >>= 1) {
        if (threadIdx.x < s) red[threadIdx.x] += red[threadIdx.x + s];
        __syncthreads();
    }
    if (threadIdx.x == 0) bsum[blockIdx.x] = red[0];
}

// phase B: exclusive scan of block sums (196 <= 256, one block)
__global__ void scanB_kernel(int* __restrict__ bsum) {
    __shared__ int sh[256];
    int tid = threadIdx.x;
    int v = (tid < SCB) ? bsum[tid] : 0;
    sh[tid] = v;
    __syncthreads();
    for (int off = 1; off < 256; off <<= 1) {
        int t = (tid >= off) ? sh[tid - off] : 0;
        __syncthreads();
        sh[tid] += t;
        __syncthreads();
    }
    if (tid < SCB) bsum[tid] = sh[tid] - v;  // exclusive
}

// phase C: block-local exclusive scan + block offset -> rowptr
__global__ void scanC_kernel(const int* __restrict__ degi, const int* __restrict__ bsum,
                             int* __restrict__ rowptr) {
    __shared__ int sh[256];
    int tid = threadIdx.x;
    int i = blockIdx.x * 256 + tid;
    int v = (i < NN) ? degi[i] : 0;
    sh[tid] = v;
    __syncthreads();
    for (int off = 1; off < 256; off <<= 1) {
        int t = (tid >= off) ? sh[tid - off] : 0;
        __syncthreads();
        sh[tid] += t;
        __syncthreads();
    }
    int excl = sh[tid] - v + bsum[blockIdx.x];
    if (i < NN) rowptr[i] = excl;
    if (i == NN - 1) rowptr[NN] = excl + v;
}

__global__ void fill_kernel(const int* __restrict__ src, const int* __restrict__ dst,
                            int* __restrict__ cursor, int* __restrict__ perm) {
    int e = blockIdx.x * 256 + threadIdx.x;
    if (e < NE) {
        int d = dst[e];
        if ((unsigned)d < NN) {
            int pos = atomicAdd(&cursor[d], 1);
            perm[pos] = src[e];
        }
    }
}

__global__ void bounds_kernel(const int* __restrict__ batch, int* __restrict__ gb) {
    int n = blockIdx.x * 256 + threadIdx.x;
    if (n >= NN) return;
    int b = batch[n];
    int bp = (n == 0) ? -1 : batch[n - 1];
    for (int g = bp + 1; g <= b; ++g) gb[g] = n;
    if (n == NN - 1)
        for (int g = b + 1; g <= NG; ++g) gb[g] = NN;
}

// ---------------- stats slot 0 = identity affine ----------------
__global__ void statsinit_kernel(float* __restrict__ stats0) {
    int c = threadIdx.x;  // 128
    stats0[256 + c] = 1.0f;  // sc
    stats0[384 + c] = 0.0f;  // sh
    stats0[512 + c] = 0.0f;  // neg = -sh/sc
}

// ---- weight prep: W' = W*scp split into bf16 hi/lo planes; bias2 = bl + shp@(Wl+Wr)^T
__global__ void wprep_kernel(const float* __restrict__ Wl, const float* __restrict__ Wr,
                             const float* __restrict__ bl, const float* __restrict__ statsP,
                             unsigned short* __restrict__ Wbh, unsigned short* __restrict__ Wbl,
                             float* __restrict__ bias2) {
    __shared__ float red[256];
    int j = blockIdx.x;   // 0..127 output channel
    int k = threadIdx.x;  // 0..255 contraction index
    float scp = statsP[256 + (k & 127)];
    float shp = statsP[384 + (k & 127)];
    float w = (k < HD) ? Wl[j * HD + k] : Wr[j * HD + (k - HD)];
    float wp = w * scp;
    unsigned short hi = f2bf(wp);
    Wbh[j * 256 + k] = hi;
    Wbl[j * 256 + k] = f2bf(wp - bf2f(hi));
    red[k] = shp * w;
    __syncthreads();
    for (int s = 128; s > 0; s >>= 1) {
        if (k < s) red[k] += red[k + s];
        __syncthreads();
    }
    if (k == 0) bias2[j] = bl[j] + red[0];
}

// ---------------- gather: agg[n] = mean over CSR row of hin[src] (all fp32) ----------
// 32 lanes per node, one float4 chunk per lane; 8-edge batching + dual accumulators
__global__ __launch_bounds__(256)
void gather_kernel(const float* __restrict__ hin, const int* __restrict__ rowptr,
                   const int* __restrict__ perm, const float* __restrict__ statsP,
                   float* __restrict__ agg) {
    int t = blockIdx.x * 256 + threadIdx.x;
    int n = t >> 5, q = t & 31;
    if (n >= NN) return;
    int r0 = rowptr[n], r1 = rowptr[n + 1];
    float4 s0 = make_float4(0.f, 0.f, 0.f, 0.f);
    float4 s1 = make_float4(0.f, 0.f, 0.f, 0.f);
    int e = r0;
    for (; e + 8 <= r1; e += 8) {
        int i0 = perm[e], i1 = perm[e + 1], i2 = perm[e + 2], i3 = perm[e + 3];
        int i4 = perm[e + 4], i5 = perm[e + 5], i6 = perm[e + 6], i7 = perm[e + 7];
        float4 v0 = ((const float4*)hin)[i0 * 32 + q];
        float4 v1 = ((const float4*)hin)[i1 * 32 + q];
        float4 v2 = ((const float4*)hin)[i2 * 32 + q];
        float4 v3 = ((const float4*)hin)[i3 * 32 + q];
        float4 v4 = ((const float4*)hin)[i4 * 32 + q];
        float4 v5 = ((const float4*)hin)[i5 * 32 + q];
        float4 v6 = ((const float4*)hin)[i6 * 32 + q];
        float4 v7 = ((const float4*)hin)[i7 * 32 + q];
        s0.x += (v0.x + v2.x) + (v4.x + v6.x);
        s0.y += (v0.y + v2.y) + (v4.y + v6.y);
        s0.z += (v0.z + v2.z) + (v4.z + v6.z);
        s0.w += (v0.w + v2.w) + (v4.w + v6.w);
        s1.x += (v1.x + v3.x) + (v5.x + v7.x);
        s1.y += (v1.y + v3.y) + (v5.y + v7.y);
        s1.z += (v1.z + v3.z) + (v5.z + v7.z);
        s1.w += (v1.w + v3.w) + (v5.w + v7.w);
    }
    for (; e + 2 <= r1; e += 2) {
        int i0 = perm[e], i1 = perm[e + 1];
        float4 v0 = ((const float4*)hin)[i0 * 32 + q];
        float4 v1 = ((const float4*)hin)[i1 * 32 + q];
        s0.x += v0.x; s0.y += v0.y; s0.z += v0.z; s0.w += v0.w;
        s1.x += v1.x; s1.y += v1.y; s1.z += v1.z; s1.w += v1.w;
    }
    if (e < r1) {
        int i0 = perm[e];
        float4 v0 = ((const float4*)hin)[i0 * 32 + q];
        s0.x += v0.x; s0.y += v0.y; s0.z += v0.z; s0.w += v0.w;
    }
    float4 s = make_float4(s0.x + s1.x, s0.y + s1.y, s0.z + s1.z, s0.w + s1.w);
    if (r1 > r0) {
        float r = 1.0f / (float)(r1 - r0);
        s.x *= r; s.y *= r; s.z *= r; s.w *= r;
    } else {
        // deg-0 sentinel: -sh/sc so the BN-folded GEMM contribution is exactly 0
        s = ((const float4*)(statsP + 512))[q];
    }
    ((float4*)agg)[n * 32 + q] = s;
}

// ---------------- split-precision MFMA GEMM ----------------
// y = relu([agg | hin] @ W'^T + bias2)  with W' = [Wl*sc | Wr*sc]
// A fp32 on the fly -> (a_hi + a_lo) bf16; 3 MFMAs per tile: hh + lh + hl.
// block = 256 thr = 4 waves; wave computes 16 rows x 128 cols, K=256.
// launch_bounds(256,3): 168-VGPR budget so the compiler can hoist A/B loads
// (grid 782 blocks = 3 blocks/CU = 3 waves/EU; latency-bound per R6 counters).
__global__ __launch_bounds__(256, 3)
void mfma_gemm(const float* __restrict__ agg, const float* __restrict__ hin,
               const unsigned short* __restrict__ Wbh, const unsigned short* __restrict__ Wbl,
               const float* __restrict__ bias2, float* __restrict__ yout,
               float* __restrict__ statsN) {
    __shared__ float ls[64 * 132];
    __shared__ float st[256];
    const int tid = threadIdx.x;
    st[tid] = 0.0f;
    __syncthreads();
    const int wave = tid >> 6, lane = tid & 63;
    const int lm = lane & 15, quad = lane >> 4;
    const int m0 = blockIdx.x * 64 + wave * 16;
    int ar = m0 + lm;
    if (ar >= NN) ar = NN - 1;  // clamp reads; invalid rows zeroed in epilogue

    f32x4 acc[8];
#pragma unroll
    for (int t = 0; t < 8; ++t) acc[t] = (f32x4){0.f, 0.f, 0.f, 0.f};

#pragma unroll
    for (int half = 0; half < 2; ++half) {
        // load + split-convert 4 chunks of A up front (independent loads in flight)
        bf16x8 ah[4], al[4];
#pragma unroll
        for (int c = 0; c < 4; ++c) {
            const int kc = half * 4 + c;
            const int k0 = kc * 32;
            const float* Abase = (kc < 4)
                ? (agg + (size_t)ar * HD + k0 + quad * 8)
                : (hin + (size_t)ar * HD + (k0 - 128) + quad * 8);
            float4 v0 = *(const float4*)(Abase);
            float4 v1 = *(const float4*)(Abase + 4);
            float av[8] = {v0.x, v0.y, v0.z, v0.w, v1.x, v1.y, v1.z, v1.w};
#pragma unroll
            for (int j = 0; j < 8; ++j) {
                unsigned short h = f2bf(av[j]);
                ah[c][j] = (short)h;
                al[c][j] = (short)f2bf(av[j] - bf2f(h));
            }
        }
#pragma unroll
        for (int c = 0; c < 4; ++c) {
            const int k0 = (half * 4 + c) * 32;
#pragma unroll
            for (int t = 0; t < 8; ++t) {
                const size_t wb = (size_t)(t * 16 + lm) * 256 + k0 + quad * 8;
                bf16x8 bh = *(const bf16x8*)(Wbh + wb);
                bf16x8 bl_ = *(const bf16x8*)(Wbl + wb);
                acc[t] = __builtin_amdgcn_mfma_f32_16x16x32_bf16(ah[c], bh, acc[t], 0, 0, 0);
                acc[t] = __builtin_amdgcn_mfma_f32_16x16x32_bf16(al[c], bh, acc[t], 0, 0, 0);
                acc[t] = __builtin_amdgcn_mfma_f32_16x16x32_bf16(ah[c], bl_, acc[t], 0, 0, 0);
            }
        }
    }

    // epilogue: bias + relu, stash fp32 tile to LDS, BN partial sums
#pragma unroll
    for (int t = 0; t < 8; ++t) {
        int n = t * 16 + lm;
        float bs = bias2[n];
        float s = 0.f, sq = 0.f;
#pragma unroll
        for (int r = 0; r < 4; ++r) {
            int gr = m0 + quad * 4 + r;
            float y = fmaxf(acc[t][r] + bs, 0.f);
            if (gr >= NN) y = 0.f;
            ls[(wave * 16 + quad * 4 + r) * 132 + n] = y;
            s += y; sq += y * y;
        }
        s += __shfl_xor(s, 16); s += __shfl_xor(s, 32);
        sq += __shfl_xor(sq, 16); sq += __shfl_xor(sq, 32);
        if (quad == 0) { atomicAdd(&st[n], s); atomicAdd(&st[128 + n], sq); }
    }
    __syncthreads();
    atomicAdd(&statsN[tid], st[tid]);

    // coalesced fp32 writeback of the 64x128 tile (float4)
#pragma unroll
    for (int it = 0; it < 8; ++it) {
        int slot = tid + it * 256;         // 2048 float4 slots
        int r = slot >> 5, q = slot & 31;
        int g = blockIdx.x * 64 + r;
        if (g < NN) {
            const float* p = &ls[r * 132 + q * 4];
            ((float4*)yout)[(size_t)g * 32 + q] = make_float4(p[0], p[1], p[2], p[3]);
        }
    }
}

// ---------------- BN prep: sc/sh/neg for NEXT layer's folding ----------------
__global__ void bnprep_kernel(float* __restrict__ statsN, const float* __restrict__ gamma,
                              const float* __restrict__ beta) {
    int c = threadIdx.x;  // 128
    float invN = 1.0f / (float)NN;
    float mu = statsN[c] * invN;
    float var = statsN[128 + c] * invN - mu * mu;
    var = var < 0.f ? 0.f : var;
    float sc = rsqrtf(var + BN_EPS) * gamma[c];
    float sh = beta[c] - mu * sc;
    statsN[256 + c] = sc;
    statsN[384 + c] = sh;
    statsN[512 + c] = (sc != 0.f) ? (-sh / sc) : 0.f;
}

// ---------------- pooling: segmented sum of pre-BN y (fp32), batch sorted ----------
__global__ __launch_bounds__(256)
void pool2_kernel(const float* __restrict__ h, const int* __restrict__ gb,
                  float* __restrict__ pooled) {
    __shared__ float red[256 * 4];
    int g = blockIdx.x >> 3, sp = blockIdx.x & 7;
    int s = gb[g], e = gb[g + 1];
    int q = threadIdx.x & 31;
    int r = threadIdx.x >> 5;
    float4 a = make_float4(0.f, 0.f, 0.f, 0.f);
    for (int n = s + sp * 8 + r; n < e; n += 64) {
        float4 v = ((const float4*)h)[n * 32 + q];
        a.x += v.x; a.y += v.y; a.z += v.z; a.w += v.w;
    }
    ((float4*)red)[r * 32 + q] = a;
    __syncthreads();
#pragma unroll
    for (int st = 4; st >= 1; st >>= 1) {
        if (r < st) {
            float4 o = ((float4*)red)[(r + st) * 32 + q];
            a.x += o.x; a.y += o.y; a.z += o.z; a.w += o.w;
            ((float4*)red)[r * 32 + q] = a;
        }
        __syncthreads();
    }
    if (r == 0) {
        float* pp = &pooled[g * HD + q * 4];
        atomicAdd(pp + 0, a.x);
        atomicAdd(pp + 1, a.y);
        atomicAdd(pp + 2, a.z);
        atomicAdd(pp + 3, a.w);
    }
}

// ---------------- head: fold layer-3 BN, dot with fcw, sigmoid ----------------
__global__ void head_kernel(const float* __restrict__ pooled, const int* __restrict__ gb,
                            const float* __restrict__ stats3, const float* __restrict__ fcw,
                            const float* __restrict__ fcb, float* __restrict__ out) {
    __shared__ float red[2];
    int g = blockIdx.x, c = threadIdx.x;  // 128 threads
    float cnt = (float)(gb[g + 1] - gb[g]);
    float v = (pooled[g * HD + c] * stats3[256 + c] + cnt * stats3[384 + c]) * fcw[c];
#pragma unroll
    for (int o = 32; o > 0; o >>= 1) v += __shfl_xor(v, o);
    if ((c & 63) == 0) red[c >> 6] = v;
    __syncthreads();
    if (c == 0) {
        float s = red[0] + red[1] + fcb[0];
        out[g] = 1.0f / (1.0f + expf(-s));
    }
}

extern "C" void kernel_launch(void* const* d_in, const int* in_sizes, int n_in,
                              void* d_out, int out_size, void* d_ws, size_t ws_size,
                              hipStream_t stream) {
    const float* x     = (const float*)d_in[0];
    const int*   ei    = (const int*)d_in[1];
    const int*   src   = ei;
    const int*   dst   = ei + NE;
    const int*   batch = (const int*)d_in[3];
    const float* Wl    = (const float*)d_in[4];
    const float* bl    = (const float*)d_in[5];
    const float* Wr    = (const float*)d_in[6];
    const float* gamma = (const float*)d_in[7];
    const float* beta  = (const float*)d_in[8];
    const float* fcw   = (const float*)d_in[9];
    const float* fcb   = (const float*)d_in[10];
    float* out = (float*)d_out;

    float* ws       = (float*)d_ws;
    float* agg      = ws;                                   // [NN][128] fp32
    float* hA       = agg + (size_t)NN * HD;                // [NN][128]
    float* hB       = hA + (size_t)NN * HD;                 // [NN][128]
    float* bias2    = hB + (size_t)NN * HD;                 // 128
    float* statsAll = bias2 + HD;                           // 4*SB
    float* pooled   = statsAll + 4 * SB;                    // NG*HD
    unsigned short* Wbh = (unsigned short*)(pooled + NG * HD);  // [128][256] bf16
    unsigned short* Wbl = Wbh + 128 * 256;                      // [128][256] bf16
    int* rowptr = (int*)(Wbl + 128 * 256);                  // NN+1
    int* cursor = rowptr + NN + 1;                          // NN (degree counts, then fill cursor)
    int* perm   = cursor + NN;                              // NE
    int* gb     = perm + NE;                                // NG+1
    int* bsum   = gb + NG + 1;                              // SCB

    hipMemsetAsync(cursor, 0, NN * sizeof(int), stream);
    hipMemsetAsync(pooled, 0, NG * HD * sizeof(float), stream);
    hipMemsetAsync(statsAll, 0, 4 * SB * sizeof(float), stream);

    degi_kernel<<<(NE + 255) / 256, 256, 0, stream>>>(dst, cursor);
    scanA_kernel<<<SCB, 256, 0, stream>>>(cursor, bsum);
    scanB_kernel<<<1, 256, 0, stream>>>(bsum);
    scanC_kernel<<<SCB, 256, 0, stream>>>(cursor, bsum, rowptr);
    hipMemcpyAsync(cursor, rowptr, NN * sizeof(int), hipMemcpyDeviceToDevice, stream);
    fill_kernel<<<(NE + 255) / 256, 256, 0, stream>>>(src, dst, cursor, perm);
    bounds_kernel<<<(NN + 255) / 256, 256, 0, stream>>>(batch, gb);
    statsinit_kernel<<<1, 128, 0, stream>>>(statsAll);

    const float* hin = x;
    float* houts[3] = {hA, hB, hA};
    for (int l = 0; l < NL; ++l) {
        float* stP = statsAll + l * SB;
        float* stN = statsAll + (l + 1) * SB;
        wprep_kernel<<<128, 256, 0, stream>>>(Wl + l * HD * HD, Wr + l * HD * HD,
                                              bl + l * HD, stP, Wbh, Wbl, bias2);
        gather_kernel<<<(NN * 32 + 255) / 256, 256, 0, stream>>>(hin, rowptr, perm, stP, agg);
        mfma_gemm<<<(NN + 63) / 64, 256, 0, stream>>>(agg, hin, Wbh, Wbl, bias2, houts[l], stN);
        bnprep_kernel<<<1, 128, 0, stream>>>(stN, gamma + l * HD, beta + l * HD);
        hin = houts[l];
    }
    pool2_kernel<<<NG * 8, 256, 0, stream>>>(hA, gb, pooled);
    head_kernel<<<NG, 128, 0, stream>>>(pooled, gb, statsAll + 3 * SB, fcw, fcb, out);
}

// Round 8
// 405.806 us; speedup vs baseline: 11.7878x; 1.5175x over previous
//
#include <hip/hip_runtime.h>
#include <math.h>

#define NN 50000
#define NE 800000
#define HD 128
#define NL 3
#define NG 64
#define BN_EPS 1e-5f
#define SB 640   // stats slot: sum[128] | sumsq[128] | sc[128] | sh[128] | neg[128]
#define SCB ((NN + 255) / 256)   // 196 scan blocks
#define WSTR 136                 // LDS weight row stride (fp16 elems): 272B -> bank-spread

typedef _Float16 f16;
typedef __attribute__((ext_vector_type(8))) _Float16 f16x8;
typedef __attribute__((ext_vector_type(4))) float f32x4;

// ---------------- CSR build ----------------
__global__ void degi_kernel(const int* __restrict__ dst, int* __restrict__ degi) {
    int e = blockIdx.x * 256 + threadIdx.x;
    if (e < NE) {
        int d = dst[e];
        if ((unsigned)d < NN) atomicAdd(&degi[d], 1);
    }
}

__global__ void scanA_kernel(const int* __restrict__ degi, int* __restrict__ bsum) {
    __shared__ int red[256];
    int i = blockIdx.x * 256 + threadIdx.x;
    red[threadIdx.x] = (i < NN) ? degi[i] : 0;
    __syncthreads();
    for (int s = 128; s > 0; s >>= 1) {
        if (threadIdx.x < s) red[threadIdx.x] += red[threadIdx.x + s];
        __syncthreads();
    }
    if (threadIdx.x == 0) bsum[blockIdx.x] = red[0];
}

__global__ void scanB_kernel(int* __restrict__ bsum) {
    __shared__ int sh[256];
    int tid = threadIdx.x;
    int v = (tid < SCB) ? bsum[tid] : 0;
    sh[tid] = v;
    __syncthreads();
    for (int off = 1; off < 256; off <<= 1) {
        int t = (tid >= off) ? sh[tid - off] : 0;
        __syncthreads();
        sh[tid] += t;
        __syncthreads();
    }
    if (tid < SCB) bsum[tid] = sh[tid] - v;  // exclusive
}

__global__ void scanC_kernel(const int* __restrict__ degi, const int* __restrict__ bsum,
                             int* __restrict__ rowptr) {
    __shared__ int sh[256];
    int tid = threadIdx.x;
    int i = blockIdx.x * 256 + tid;
    int v = (i < NN) ? degi[i] : 0;
    sh[tid] = v;
    __syncthreads();
    for (int off = 1; off < 256; off <<= 1) {
        int t = (tid >= off) ? sh[tid - off] : 0;
        __syncthreads();
        sh[tid] += t;
        __syncthreads();
    }
    int excl = sh[tid] - v + bsum[blockIdx.x];
    if (i < NN) rowptr[i] = excl;
    if (i == NN - 1) rowptr[NN] = excl + v;
}

__global__ void fill_kernel(const int* __restrict__ src, const int* __restrict__ dst,
                            int* __restrict__ cursor, int* __restrict__ perm) {
    int e = blockIdx.x * 256 + threadIdx.x;
    if (e < NE) {
        int d = dst[e];
        if ((unsigned)d < NN) {
            int pos = atomicAdd(&cursor[d], 1);
            perm[pos] = src[e];
        }
    }
}

__global__ void bounds_kernel(const int* __restrict__ batch, int* __restrict__ gb) {
    int n = blockIdx.x * 256 + threadIdx.x;
    if (n >= NN) return;
    int b = batch[n];
    int bp = (n == 0) ? -1 : batch[n - 1];
    for (int g = bp + 1; g <= b; ++g) gb[g] = n;
    if (n == NN - 1)
        for (int g = b + 1; g <= NG; ++g) gb[g] = NN;
}

// ---------------- stats slot 0 = identity affine ----------------
__global__ void statsinit_kernel(float* __restrict__ stats0) {
    int c = threadIdx.x;  // 128
    stats0[256 + c] = 1.0f;  // sc
    stats0[384 + c] = 0.0f;  // sh
    stats0[512 + c] = 0.0f;  // neg = -sh/sc
}

// ---------------- x (fp32) -> hf (fp16 rows) ----------------
__global__ void cvt_kernel(const float* __restrict__ x, f16* __restrict__ hf) {
    int t = blockIdx.x * 256 + threadIdx.x;
    if (t >= NN * 16) return;
    int n = t >> 4, q = t & 15;
    float4 v0 = ((const float4*)x)[n * 32 + q * 2];
    float4 v1 = ((const float4*)x)[n * 32 + q * 2 + 1];
    f16x8 o;
    o[0] = (f16)v0.x; o[1] = (f16)v0.y; o[2] = (f16)v0.z; o[3] = (f16)v0.w;
    o[4] = (f16)v1.x; o[5] = (f16)v1.y; o[6] = (f16)v1.z; o[7] = (f16)v1.w;
    *(f16x8*)(hf + (size_t)n * HD + q * 8) = o;
}

// ---- weight prep: Wh[j][k] = fp16(W[j][k]*scp[k]); bias2 = bl + shp@(Wl+Wr)^T ----
__global__ void wprep_kernel(const float* __restrict__ Wl, const float* __restrict__ Wr,
                             const float* __restrict__ bl, const float* __restrict__ statsP,
                             f16* __restrict__ Wh, float* __restrict__ bias2) {
    __shared__ float red[256];
    int j = blockIdx.x;   // 0..127 output channel
    int k = threadIdx.x;  // 0..255 contraction index
    float scp = statsP[256 + (k & 127)];
    float shp = statsP[384 + (k & 127)];
    float w = (k < HD) ? Wl[j * HD + k] : Wr[j * HD + (k - HD)];
    Wh[j * 256 + k] = (f16)(w * scp);
    red[k] = shp * w;
    __syncthreads();
    for (int s = 128; s > 0; s >>= 1) {
        if (k < s) red[k] += red[k + s];
        __syncthreads();
    }
    if (k == 0) bias2[j] = bl[j] + red[0];
}

// ---------------- gather: aggf[n] = fp16(mean over CSR row of hf[src]) ----------
// 16 lanes per node, 8 fp16 channels (16 B) per lane; fp32 accumulate; 8-edge batch
__global__ __launch_bounds__(256)
void gather_kernel(const f16* __restrict__ hf, const int* __restrict__ rowptr,
                   const int* __restrict__ perm, const float* __restrict__ statsP,
                   f16* __restrict__ aggf) {
    int t = blockIdx.x * 256 + threadIdx.x;
    int n = t >> 4, q = t & 15;
    if (n >= NN) return;
    int r0 = rowptr[n], r1 = rowptr[n + 1];
    float sA[8] = {0.f, 0.f, 0.f, 0.f, 0.f, 0.f, 0.f, 0.f};
    float sB[8] = {0.f, 0.f, 0.f, 0.f, 0.f, 0.f, 0.f, 0.f};
    int e = r0;
    for (; e + 8 <= r1; e += 8) {
        int i0 = perm[e], i1 = perm[e + 1], i2 = perm[e + 2], i3 = perm[e + 3];
        int i4 = perm[e + 4], i5 = perm[e + 5], i6 = perm[e + 6], i7 = perm[e + 7];
        f16x8 v0 = *(const f16x8*)(hf + (size_t)i0 * HD + q * 8);
        f16x8 v1 = *(const f16x8*)(hf + (size_t)i1 * HD + q * 8);
        f16x8 v2 = *(const f16x8*)(hf + (size_t)i2 * HD + q * 8);
        f16x8 v3 = *(const f16x8*)(hf + (size_t)i3 * HD + q * 8);
        f16x8 v4 = *(const f16x8*)(hf + (size_t)i4 * HD + q * 8);
        f16x8 v5 = *(const f16x8*)(hf + (size_t)i5 * HD + q * 8);
        f16x8 v6 = *(const f16x8*)(hf + (size_t)i6 * HD + q * 8);
        f16x8 v7 = *(const f16x8*)(hf + (size_t)i7 * HD + q * 8);
#pragma unroll
        for (int j = 0; j < 8; ++j) {
            sA[j] += ((float)v0[j] + (float)v2[j]) + ((float)v4[j] + (float)v6[j]);
            sB[j] += ((float)v1[j] + (float)v3[j]) + ((float)v5[j] + (float)v7[j]);
        }
    }
    for (; e + 2 <= r1; e += 2) {
        int i0 = perm[e], i1 = perm[e + 1];
        f16x8 v0 = *(const f16x8*)(hf + (size_t)i0 * HD + q * 8);
        f16x8 v1 = *(const f16x8*)(hf + (size_t)i1 * HD + q * 8);
#pragma unroll
        for (int j = 0; j < 8; ++j) { sA[j] += (float)v0[j]; sB[j] += (float)v1[j]; }
    }
    if (e < r1) {
        int i0 = perm[e];
        f16x8 v0 = *(const f16x8*)(hf + (size_t)i0 * HD + q * 8);
#pragma unroll
        for (int j = 0; j < 8; ++j) sA[j] += (float)v0[j];
    }
    float s[8];
#pragma unroll
    for (int j = 0; j < 8; ++j) s[j] = sA[j] + sB[j];
    if (r1 > r0) {
        float r = 1.0f / (float)(r1 - r0);
#pragma unroll
        for (int j = 0; j < 8; ++j) s[j] *= r;
    } else {
        const float* neg = statsP + 512;  // -sh/sc sentinel: BN-folded GEMM contribution = 0
#pragma unroll
        for (int j = 0; j < 8; ++j) s[j] = neg[q * 8 + j];
    }
    f16x8 o;
#pragma unroll
    for (int j = 0; j < 8; ++j) o[j] = (f16)s[j];
    *(f16x8*)(aggf + (size_t)n * HD + q * 8) = o;
}

// ---------------- fp16 MFMA GEMM, B staged in LDS ----------------
// y = relu([aggf | hf] @ Wh^T + bias2); A fp16 [NN][128]x2, Wh fp16 [128][256].
// block = 256 thr = 4 waves; wave: 16 rows x 128 cols; K in 2 halves of 128,
// weights half staged to LDS (34.8 KB, stride WSTR), LDS reused for f32 epilogue.
__global__ __launch_bounds__(256, 4)
void mfma_gemm(const f16* __restrict__ aggf, const f16* __restrict__ hf,
               const f16* __restrict__ Wh, const float* __restrict__ bias2,
               f16* __restrict__ yout, float* __restrict__ statsN) {
    __shared__ f16 wls[128 * WSTR];   // 34816 B; aliased as f32 ls[64][132] in epilogue
    __shared__ float st[256];
    float* ls = (float*)wls;
    const int tid = threadIdx.x;
    st[tid] = 0.0f;
    const int wave = tid >> 6, lane = tid & 63;
    const int lm = lane & 15, quad = lane >> 4;
    const int m0 = blockIdx.x * 64 + wave * 16;
    int ar = m0 + lm;
    if (ar >= NN) ar = NN - 1;  // clamp reads; invalid rows zeroed in epilogue

    f32x4 acc[8];
#pragma unroll
    for (int t = 0; t < 8; ++t) acc[t] = (f32x4){0.f, 0.f, 0.f, 0.f};

#pragma unroll
    for (int half = 0; half < 2; ++half) {
        __syncthreads();
        // stage this K-half of Wh: 128 rows x 128 fp16 = 32 KB, 8 x 16B per thread
#pragma unroll
        for (int it = 0; it < 8; ++it) {
            int slot = tid + it * 256;            // 2048 slots of 16 B
            int r = slot >> 4, c = slot & 15;
            *(f16x8*)&wls[r * WSTR + c * 8] =
                *(const f16x8*)(Wh + (size_t)r * 256 + half * 128 + c * 8);
        }
        __syncthreads();
        // prefetch A fragments for all 4 chunks of this half
        f16x8 a[4];
#pragma unroll
        for (int c = 0; c < 4; ++c) {
            const f16* Ab = (half == 0)
                ? (aggf + (size_t)ar * HD + c * 32 + quad * 8)
                : (hf   + (size_t)ar * HD + c * 32 + quad * 8);
            a[c] = *(const f16x8*)Ab;
        }
#pragma unroll
        for (int c = 0; c < 4; ++c) {
#pragma unroll
            for (int t = 0; t < 8; ++t) {
                f16x8 b = *(const f16x8*)&wls[(t * 16 + lm) * WSTR + c * 32 + quad * 8];
                acc[t] = __builtin_amdgcn_mfma_f32_16x16x32_f16(a[c], b, acc[t], 0, 0, 0);
            }
        }
    }
    __syncthreads();  // weights no longer needed; wls becomes the f32 epilogue tile

    // epilogue: bias + relu, stash f32 tile to LDS, BN partial sums
#pragma unroll
    for (int t = 0; t < 8; ++t) {
        int n = t * 16 + lm;
        float bs = bias2[n];
        float s = 0.f, sq = 0.f;
#pragma unroll
        for (int r = 0; r < 4; ++r) {
            int gr = m0 + quad * 4 + r;
            float y = fmaxf(acc[t][r] + bs, 0.f);
            if (gr >= NN) y = 0.f;
            ls[(wave * 16 + quad * 4 + r) * 132 + n] = y;
            s += y; sq += y * y;
        }
        s += __shfl_xor(s, 16); s += __shfl_xor(s, 32);
        sq += __shfl_xor(sq, 16); sq += __shfl_xor(sq, 32);
        if (quad == 0) { atomicAdd(&st[n], s); atomicAdd(&st[128 + n], sq); }
    }
    __syncthreads();
    atomicAdd(&statsN[tid], st[tid]);

    // coalesced fp16 writeback: 64 rows x 128 ch = 1024 x 16B slots, 4 per thread
#pragma unroll
    for (int it = 0; it < 4; ++it) {
        int slot = tid + it * 256;
        int r = slot >> 4, c = slot & 15;
        int g = blockIdx.x * 64 + r;
        if (g < NN) {
            const float* p = &ls[r * 132 + c * 8];
            f16x8 o;
#pragma unroll
            for (int j = 0; j < 8; ++j) o[j] = (f16)p[j];
            *(f16x8*)(yout + (size_t)g * HD + c * 8) = o;
        }
    }
}

// ---------------- BN prep: sc/sh/neg for NEXT layer's folding ----------------
__global__ void bnprep_kernel(float* __restrict__ statsN, const float* __restrict__ gamma,
                              const float* __restrict__ beta) {
    int c = threadIdx.x;  // 128
    float invN = 1.0f / (float)NN;
    float mu = statsN[c] * invN;
    float var = statsN[128 + c] * invN - mu * mu;
    var = var < 0.f ? 0.f : var;
    float sc = rsqrtf(var + BN_EPS) * gamma[c];
    float sh = beta[c] - mu * sc;
    statsN[256 + c] = sc;
    statsN[384 + c] = sh;
    statsN[512 + c] = (sc != 0.f) ? (-sh / sc) : 0.f;
}

// ---------------- pooling: segmented sum of fp16 h3, fp32 accumulate ----------
__global__ __launch_bounds__(256)
void pool2_kernel(const f16* __restrict__ hf, const int* __restrict__ gb,
                  float* __restrict__ pooled) {
    __shared__ float red[16 * 128];
    int g = blockIdx.x >> 3, sp = blockIdx.x & 7;
    int s = gb[g], e = gb[g + 1];
    int q = threadIdx.x & 15, r = threadIdx.x >> 4;
    float a[8] = {0.f, 0.f, 0.f, 0.f, 0.f, 0.f, 0.f, 0.f};
    for (int n = s + sp * 16 + r; n < e; n += 128) {
        f16x8 v = *(const f16x8*)(hf + (size_t)n * HD + q * 8);
#pragma unroll
        for (int j = 0; j < 8; ++j) a[j] += (float)v[j];
    }
#pragma unroll
    for (int j = 0; j < 8; ++j) red[r * 128 + q * 8 + j] = a[j];
    __syncthreads();
    for (int stp = 8; stp >= 1; stp >>= 1) {
        if (r < stp) {
#pragma unroll
            for (int j = 0; j < 8; ++j)
                red[r * 128 + q * 8 + j] += red[(r + stp) * 128 + q * 8 + j];
        }
        __syncthreads();
    }
    if (r == 0) {
#pragma unroll
        for (int j = 0; j < 8; ++j) atomicAdd(&pooled[g * HD + q * 8 + j], red[q * 8 + j]);
    }
}

// ---------------- head: fold layer-3 BN, dot with fcw, sigmoid ----------------
__global__ void head_kernel(const float* __restrict__ pooled, const int* __restrict__ gb,
                            const float* __restrict__ stats3, const float* __restrict__ fcw,
                            const float* __restrict__ fcb, float* __restrict__ out) {
    __shared__ float red[2];
    int g = blockIdx.x, c = threadIdx.x;  // 128 threads
    float cnt = (float)(gb[g + 1] - gb[g]);
    float v = (pooled[g * HD + c] * stats3[256 + c] + cnt * stats3[384 + c]) * fcw[c];
#pragma unroll
    for (int o = 32; o > 0; o >>= 1) v += __shfl_xor(v, o);
    if ((c & 63) == 0) red[c >> 6] = v;
    __syncthreads();
    if (c == 0) {
        float s = red[0] + red[1] + fcb[0];
        out[g] = 1.0f / (1.0f + expf(-s));
    }
}

extern "C" void kernel_launch(void* const* d_in, const int* in_sizes, int n_in,
                              void* d_out, int out_size, void* d_ws, size_t ws_size,
                              hipStream_t stream) {
    const float* x     = (const float*)d_in[0];
    const int*   ei    = (const int*)d_in[1];
    const int*   src   = ei;
    const int*   dst   = ei + NE;
    const int*   batch = (const int*)d_in[3];
    const float* Wl    = (const float*)d_in[4];
    const float* bl    = (const float*)d_in[5];
    const float* Wr    = (const float*)d_in[6];
    const float* gamma = (const float*)d_in[7];
    const float* beta  = (const float*)d_in[8];
    const float* fcw   = (const float*)d_in[9];
    const float* fcb   = (const float*)d_in[10];
    float* out = (float*)d_out;

    f16* hf0  = (f16*)d_ws;                       // [NN][128] fp16 (x converted)
    f16* hfA  = hf0 + (size_t)NN * HD;            // [NN][128]
    f16* hfB  = hfA + (size_t)NN * HD;            // [NN][128]
    f16* aggf = hfB + (size_t)NN * HD;            // [NN][128]
    f16* Wh   = aggf + (size_t)NN * HD;           // [128][256] fp16
    float* bias2    = (float*)(Wh + 128 * 256);   // 128
    float* statsAll = bias2 + HD;                 // 4*SB
    float* pooled   = statsAll + 4 * SB;          // NG*HD
    int* rowptr = (int*)(pooled + NG * HD);       // NN+1
    int* cursor = rowptr + NN + 1;                // NN
    int* perm   = cursor + NN;                    // NE
    int* gb     = perm + NE;                      // NG+1
    int* bsum   = gb + NG + 1;                    // SCB

    hipMemsetAsync(cursor, 0, NN * sizeof(int), stream);
    hipMemsetAsync(pooled, 0, NG * HD * sizeof(float), stream);
    hipMemsetAsync(statsAll, 0, 4 * SB * sizeof(float), stream);

    degi_kernel<<<(NE + 255) / 256, 256, 0, stream>>>(dst, cursor);
    scanA_kernel<<<SCB, 256, 0, stream>>>(cursor, bsum);
    scanB_kernel<<<1, 256, 0, stream>>>(bsum);
    scanC_kernel<<<SCB, 256, 0, stream>>>(cursor, bsum, rowptr);
    hipMemcpyAsync(cursor, rowptr, NN * sizeof(int), hipMemcpyDeviceToDevice, stream);
    fill_kernel<<<(NE + 255) / 256, 256, 0, stream>>>(src, dst, cursor, perm);
    bounds_kernel<<<(NN + 255) / 256, 256, 0, stream>>>(batch, gb);
    statsinit_kernel<<<1, 128, 0, stream>>>(statsAll);
    cvt_kernel<<<(NN * 16 + 255) / 256, 256, 0, stream>>>(x, hf0);

    const f16* hin = hf0;
    f16* houts[3] = {hfA, hfB, hfA};
    for (int l = 0; l < NL; ++l) {
        float* stP = statsAll + l * SB;
        float* stN = statsAll + (l + 1) * SB;
        wprep_kernel<<<128, 256, 0, stream>>>(Wl + l * HD * HD, Wr + l * HD * HD,
                                              bl + l * HD, stP, Wh, bias2);
        gather_kernel<<<(NN * 16 + 255) / 256, 256, 0, stream>>>(hin, rowptr, perm, stP, aggf);
        mfma_gemm<<<(NN + 63) / 64, 256, 0, stream>>>(aggf, hin, Wh, bias2, houts[l], stN);
        bnprep_kernel<<<1, 128, 0, stream>>>(stN, gamma + l * HD, beta + l * HD);
        hin = houts[l];
    }
    pool2_kernel<<<NG * 8, 256, 0, stream>>>(hfA, gb, pooled);
    head_kernel<<<NG, 128, 0, stream>>>(pooled, gb, statsAll + 3 * SB, fcw, fcb, out);
}

// Round 9
// 350.067 us; speedup vs baseline: 13.6647x; 1.1592x over previous
//
#include <hip/hip_runtime.h>
#include <math.h>

#define NN 50000
#define NE 800000
#define HD 128
#define NL 3
#define NG 64
#define BN_EPS 1e-5f
#define SB 640   // stats slot: sum[128] | sumsq[128] | sc[128] | sh[128] | neg[128]
#define NB 196   // dst buckets of 256 nodes: ceil(NN/256)
#define EPB 4096 // edges per block in bucket passes: 196 blocks
#define MAXB 8192 // LDS perm-window capacity (bucket avg 4082, sigma ~64)
#define WSTR 136 // LDS weight row stride (fp16 elems)

typedef _Float16 f16;
typedef __attribute__((ext_vector_type(8))) _Float16 f16x8;
typedef __attribute__((ext_vector_type(4))) float f32x4;

// ================= CSR build: bucketed counting sort =================
// phase 0: global bucket histogram via per-block LDS histograms
__global__ __launch_bounds__(256)
void buckcnt_kernel(const int* __restrict__ dst, int* __restrict__ bcnt) {
    __shared__ int h[NB];
    for (int i = threadIdx.x; i < NB; i += 256) h[i] = 0;
    __syncthreads();
    int base = blockIdx.x * EPB;
#pragma unroll
    for (int it = 0; it < EPB / 256; ++it) {
        int e = base + it * 256 + threadIdx.x;
        if (e < NE) atomicAdd(&h[dst[e] >> 8], 1);
    }
    __syncthreads();
    for (int i = threadIdx.x; i < NB; i += 256)
        if (h[i]) atomicAdd(&bcnt[i], h[i]);
}

// phase 1: exclusive scan of 196 bucket counts -> bbase, init bcur
__global__ void buckscan_kernel(const int* __restrict__ bcnt, int* __restrict__ bbase,
                                int* __restrict__ bcur) {
    __shared__ int sh[256];
    int tid = threadIdx.x;
    int v = (tid < NB) ? bcnt[tid] : 0;
    sh[tid] = v;
    __syncthreads();
    for (int off = 1; off < 256; off <<= 1) {
        int t = (tid >= off) ? sh[tid - off] : 0;
        __syncthreads();
        sh[tid] += t;
        __syncthreads();
    }
    int excl = sh[tid] - v;
    if (tid < NB) { bbase[tid] = excl; bcur[tid] = excl; }
    if (tid == NB - 1) bbase[NB] = excl + v;  // == NE
}

// phase 2: scatter packed (dst<<16|src) into bucket-contiguous staging.
// per-block LDS histogram -> one global atomic per bucket reserves a contiguous
// run -> run writes are coalesced 64B streams (vs 800K random 4B sectors).
__global__ __launch_bounds__(256)
void buckscat_kernel(const int* __restrict__ src, const int* __restrict__ dst,
                     int* __restrict__ bcur, unsigned* __restrict__ staging) {
    __shared__ int h[NB];
    __shared__ int rbase[NB];
    for (int i = threadIdx.x; i < NB; i += 256) h[i] = 0;
    __syncthreads();
    int base = blockIdx.x * EPB;
#pragma unroll
    for (int it = 0; it < EPB / 256; ++it) {
        int e = base + it * 256 + threadIdx.x;
        if (e < NE) atomicAdd(&h[dst[e] >> 8], 1);
    }
    __syncthreads();
    for (int i = threadIdx.x; i < NB; i += 256) {
        rbase[i] = h[i] ? atomicAdd(&bcur[i], h[i]) : 0;
        h[i] = 0;
    }
    __syncthreads();
#pragma unroll
    for (int it = 0; it < EPB / 256; ++it) {
        int e = base + it * 256 + threadIdx.x;
        if (e < NE) {
            int d = dst[e];
            int k = d >> 8;
            int p = rbase[k] + atomicAdd(&h[k], 1);
            staging[p] = ((unsigned)d << 16) | (unsigned)src[e];
        }
    }
}

// phase 3: one block per bucket: per-dst counts + prefix (-> rowptr), scatter
// src into LDS window, coalesced perm writeback.
__global__ __launch_bounds__(256)
void buckbuild_kernel(const unsigned* __restrict__ staging, const int* __restrict__ bbase,
                      int* __restrict__ rowptr, int* __restrict__ perm) {
    __shared__ int cnt[256];
    __shared__ int pre[256];
    __shared__ unsigned short lperm[MAXB];
    const int k = blockIdx.x;
    const int s = bbase[k], e = bbase[k + 1];
    const int size = e - s;
    const int tid = threadIdx.x;
    cnt[tid] = 0;
    __syncthreads();
    for (int i = s + tid; i < e; i += 256)
        atomicAdd(&cnt[(int)(staging[i] >> 16) - k * 256], 1);
    __syncthreads();
    int v = cnt[tid];
    pre[tid] = v;
    __syncthreads();
    for (int off = 1; off < 256; off <<= 1) {
        int t = (tid >= off) ? pre[tid - off] : 0;
        __syncthreads();
        pre[tid] += t;
        __syncthreads();
    }
    int excl = pre[tid] - v;
    int n = k * 256 + tid;
    if (n < NN) rowptr[n] = s + excl;
    if (n == NN - 1) rowptr[NN] = NE;
    cnt[tid] = excl;  // reuse as scatter cursors
    __syncthreads();
    if (size <= MAXB) {
        for (int i = s + tid; i < e; i += 256) {
            unsigned w = staging[i];
            int dl = (int)(w >> 16) - k * 256;
            int p = atomicAdd(&cnt[dl], 1);
            lperm[p] = (unsigned short)(w & 0xffffu);
        }
        __syncthreads();
        for (int i = tid; i < size; i += 256) perm[s + i] = (int)lperm[i];
    } else {  // safety fallback (statistically unreachable)
        for (int i = s + tid; i < e; i += 256) {
            unsigned w = staging[i];
            int dl = (int)(w >> 16) - k * 256;
            int p = atomicAdd(&cnt[dl], 1);
            perm[s + p] = (int)(w & 0xffffu);
        }
    }
}

// ================= misc prep =================
__global__ void bounds_kernel(const int* __restrict__ batch, int* __restrict__ gb) {
    int n = blockIdx.x * 256 + threadIdx.x;
    if (n >= NN) return;
    int b = batch[n];
    int bp = (n == 0) ? -1 : batch[n - 1];
    for (int g = bp + 1; g <= b; ++g) gb[g] = n;
    if (n == NN - 1)
        for (int g = b + 1; g <= NG; ++g) gb[g] = NN;
}

__global__ void statsinit_kernel(float* __restrict__ stats0) {
    int c = threadIdx.x;  // 128
    stats0[256 + c] = 1.0f;  // sc
    stats0[384 + c] = 0.0f;  // sh
    stats0[512 + c] = 0.0f;  // neg = -sh/sc
}

__global__ void cvt_kernel(const float* __restrict__ x, f16* __restrict__ hf) {
    int t = blockIdx.x * 256 + threadIdx.x;
    if (t >= NN * 16) return;
    int n = t >> 4, q = t & 15;
    float4 v0 = ((const float4*)x)[n * 32 + q * 2];
    float4 v1 = ((const float4*)x)[n * 32 + q * 2 + 1];
    f16x8 o;
    o[0] = (f16)v0.x; o[1] = (f16)v0.y; o[2] = (f16)v0.z; o[3] = (f16)v0.w;
    o[4] = (f16)v1.x; o[5] = (f16)v1.y; o[6] = (f16)v1.z; o[7] = (f16)v1.w;
    *(f16x8*)(hf + (size_t)n * HD + q * 8) = o;
}

// ---- weight prep: Wh[j][k] = fp16(W[j][k]*scp[k]); bias2 = bl + shp@(Wl+Wr)^T ----
__global__ void wprep_kernel(const float* __restrict__ Wl, const float* __restrict__ Wr,
                             const float* __restrict__ bl, const float* __restrict__ statsP,
                             f16* __restrict__ Wh, float* __restrict__ bias2) {
    __shared__ float red[256];
    int j = blockIdx.x;   // 0..127 output channel
    int k = threadIdx.x;  // 0..255 contraction index
    float scp = statsP[256 + (k & 127)];
    float shp = statsP[384 + (k & 127)];
    float w = (k < HD) ? Wl[j * HD + k] : Wr[j * HD + (k - HD)];
    Wh[j * 256 + k] = (f16)(w * scp);
    red[k] = shp * w;
    __syncthreads();
    for (int s = 128; s > 0; s >>= 1) {
        if (k < s) red[k] += red[k + s];
        __syncthreads();
    }
    if (k == 0) bias2[j] = bl[j] + red[0];
}

// ---------------- gather: aggf[n] = fp16(mean over CSR row of hf[src]) ----------
__global__ __launch_bounds__(256)
void gather_kernel(const f16* __restrict__ hf, const int* __restrict__ rowptr,
                   const int* __restrict__ perm, const float* __restrict__ statsP,
                   f16* __restrict__ aggf) {
    int t = blockIdx.x * 256 + threadIdx.x;
    int n = t >> 4, q = t & 15;
    if (n >= NN) return;
    int r0 = rowptr[n], r1 = rowptr[n + 1];
    float sA[8] = {0.f, 0.f, 0.f, 0.f, 0.f, 0.f, 0.f, 0.f};
    float sB[8] = {0.f, 0.f, 0.f, 0.f, 0.f, 0.f, 0.f, 0.f};
    int e = r0;
    for (; e + 8 <= r1; e += 8) {
        int i0 = perm[e], i1 = perm[e + 1], i2 = perm[e + 2], i3 = perm[e + 3];
        int i4 = perm[e + 4], i5 = perm[e + 5], i6 = perm[e + 6], i7 = perm[e + 7];
        f16x8 v0 = *(const f16x8*)(hf + (size_t)i0 * HD + q * 8);
        f16x8 v1 = *(const f16x8*)(hf + (size_t)i1 * HD + q * 8);
        f16x8 v2 = *(const f16x8*)(hf + (size_t)i2 * HD + q * 8);
        f16x8 v3 = *(const f16x8*)(hf + (size_t)i3 * HD + q * 8);
        f16x8 v4 = *(const f16x8*)(hf + (size_t)i4 * HD + q * 8);
        f16x8 v5 = *(const f16x8*)(hf + (size_t)i5 * HD + q * 8);
        f16x8 v6 = *(const f16x8*)(hf + (size_t)i6 * HD + q * 8);
        f16x8 v7 = *(const f16x8*)(hf + (size_t)i7 * HD + q * 8);
#pragma unroll
        for (int j = 0; j < 8; ++j) {
            sA[j] += ((float)v0[j] + (float)v2[j]) + ((float)v4[j] + (float)v6[j]);
            sB[j] += ((float)v1[j] + (float)v3[j]) + ((float)v5[j] + (float)v7[j]);
        }
    }
    for (; e + 2 <= r1; e += 2) {
        int i0 = perm[e], i1 = perm[e + 1];
        f16x8 v0 = *(const f16x8*)(hf + (size_t)i0 * HD + q * 8);
        f16x8 v1 = *(const f16x8*)(hf + (size_t)i1 * HD + q * 8);
#pragma unroll
        for (int j = 0; j < 8; ++j) { sA[j] += (float)v0[j]; sB[j] += (float)v1[j]; }
    }
    if (e < r1) {
        int i0 = perm[e];
        f16x8 v0 = *(const f16x8*)(hf + (size_t)i0 * HD + q * 8);
#pragma unroll
        for (int j = 0; j < 8; ++j) sA[j] += (float)v0[j];
    }
    float s[8];
#pragma unroll
    for (int j = 0; j < 8; ++j) s[j] = sA[j] + sB[j];
    if (r1 > r0) {
        float r = 1.0f / (float)(r1 - r0);
#pragma unroll
        for (int j = 0; j < 8; ++j) s[j] *= r;
    } else {
        const float* neg = statsP + 512;  // -sh/sc sentinel: BN-folded GEMM contribution = 0
#pragma unroll
        for (int j = 0; j < 8; ++j) s[j] = neg[q * 8 + j];
    }
    f16x8 o;
#pragma unroll
    for (int j = 0; j < 8; ++j) o[j] = (f16)s[j];
    *(f16x8*)(aggf + (size_t)n * HD + q * 8) = o;
}

// ---------------- fp16 MFMA GEMM, B staged in LDS ----------------
__global__ __launch_bounds__(256, 4)
void mfma_gemm(const f16* __restrict__ aggf, const f16* __restrict__ hf,
               const f16* __restrict__ Wh, const float* __restrict__ bias2,
               f16* __restrict__ yout, float* __restrict__ statsN) {
    __shared__ f16 wls[128 * WSTR];   // 34816 B; aliased as f32 ls[64][132] in epilogue
    __shared__ float st[256];
    float* ls = (float*)wls;
    const int tid = threadIdx.x;
    st[tid] = 0.0f;
    const int wave = tid >> 6, lane = tid & 63;
    const int lm = lane & 15, quad = lane >> 4;
    const int m0 = blockIdx.x * 64 + wave * 16;
    int ar = m0 + lm;
    if (ar >= NN) ar = NN - 1;  // clamp reads; invalid rows zeroed in epilogue

    f32x4 acc[8];
#pragma unroll
    for (int t = 0; t < 8; ++t) acc[t] = (f32x4){0.f, 0.f, 0.f, 0.f};

#pragma unroll
    for (int half = 0; half < 2; ++half) {
        __syncthreads();
#pragma unroll
        for (int it = 0; it < 8; ++it) {
            int slot = tid + it * 256;            // 2048 slots of 16 B
            int r = slot >> 4, c = slot & 15;
            *(f16x8*)&wls[r * WSTR + c * 8] =
                *(const f16x8*)(Wh + (size_t)r * 256 + half * 128 + c * 8);
        }
        __syncthreads();
        f16x8 a[4];
#pragma unroll
        for (int c = 0; c < 4; ++c) {
            const f16* Ab = (half == 0)
                ? (aggf + (size_t)ar * HD + c * 32 + quad * 8)
                : (hf   + (size_t)ar * HD + c * 32 + quad * 8);
            a[c] = *(const f16x8*)Ab;
        }
#pragma unroll
        for (int c = 0; c < 4; ++c) {
#pragma unroll
            for (int t = 0; t < 8; ++t) {
                f16x8 b = *(const f16x8*)&wls[(t * 16 + lm) * WSTR + c * 32 + quad * 8];
                acc[t] = __builtin_amdgcn_mfma_f32_16x16x32_f16(a[c], b, acc[t], 0, 0, 0);
            }
        }
    }
    __syncthreads();  // weights done; wls becomes f32 epilogue tile

#pragma unroll
    for (int t = 0; t < 8; ++t) {
        int n = t * 16 + lm;
        float bs = bias2[n];
        float s = 0.f, sq = 0.f;
#pragma unroll
        for (int r = 0; r < 4; ++r) {
            int gr = m0 + quad * 4 + r;
            float y = fmaxf(acc[t][r] + bs, 0.f);
            if (gr >= NN) y = 0.f;
            ls[(wave * 16 + quad * 4 + r) * 132 + n] = y;
            s += y; sq += y * y;
        }
        s += __shfl_xor(s, 16); s += __shfl_xor(s, 32);
        sq += __shfl_xor(sq, 16); sq += __shfl_xor(sq, 32);
        if (quad == 0) { atomicAdd(&st[n], s); atomicAdd(&st[128 + n], sq); }
    }
    __syncthreads();
    atomicAdd(&statsN[tid], st[tid]);

#pragma unroll
    for (int it = 0; it < 4; ++it) {
        int slot = tid + it * 256;
        int r = slot >> 4, c = slot & 15;
        int g = blockIdx.x * 64 + r;
        if (g < NN) {
            const float* p = &ls[r * 132 + c * 8];
            f16x8 o;
#pragma unroll
            for (int j = 0; j < 8; ++j) o[j] = (f16)p[j];
            *(f16x8*)(yout + (size_t)g * HD + c * 8) = o;
        }
    }
}

// ---------------- BN prep ----------------
__global__ void bnprep_kernel(float* __restrict__ statsN, const float* __restrict__ gamma,
                              const float* __restrict__ beta) {
    int c = threadIdx.x;  // 128
    float invN = 1.0f / (float)NN;
    float mu = statsN[c] * invN;
    float var = statsN[128 + c] * invN - mu * mu;
    var = var < 0.f ? 0.f : var;
    float sc = rsqrtf(var + BN_EPS) * gamma[c];
    float sh = beta[c] - mu * sc;
    statsN[256 + c] = sc;
    statsN[384 + c] = sh;
    statsN[512 + c] = (sc != 0.f) ? (-sh / sc) : 0.f;
}

// ---------------- pooling ----------------
__global__ __launch_bounds__(256)
void pool2_kernel(const f16* __restrict__ hf, const int* __restrict__ gb,
                  float* __restrict__ pooled) {
    __shared__ float red[16 * 128];
    int g = blockIdx.x >> 3, sp = blockIdx.x & 7;
    int s = gb[g], e = gb[g + 1];
    int q = threadIdx.x & 15, r = threadIdx.x >> 4;
    float a[8] = {0.f, 0.f, 0.f, 0.f, 0.f, 0.f, 0.f, 0.f};
    for (int n = s + sp * 16 + r; n < e; n += 128) {
        f16x8 v = *(const f16x8*)(hf + (size_t)n * HD + q * 8);
#pragma unroll
        for (int j = 0; j < 8; ++j) a[j] += (float)v[j];
    }
#pragma unroll
    for (int j = 0; j < 8; ++j) red[r * 128 + q * 8 + j] = a[j];
    __syncthreads();
    for (int stp = 8; stp >= 1; stp >>= 1) {
        if (r < stp) {
#pragma unroll
            for (int j = 0; j < 8; ++j)
                red[r * 128 + q * 8 + j] += red[(r + stp) * 128 + q * 8 + j];
        }
        __syncthreads();
    }
    if (r == 0) {
#pragma unroll
        for (int j = 0; j < 8; ++j) atomicAdd(&pooled[g * HD + q * 8 + j], red[q * 8 + j]);
    }
}

// ---------------- head ----------------
__global__ void head_kernel(const float* __restrict__ pooled, const int* __restrict__ gb,
                            const float* __restrict__ stats3, const float* __restrict__ fcw,
                            const float* __restrict__ fcb, float* __restrict__ out) {
    __shared__ float red[2];
    int g = blockIdx.x, c = threadIdx.x;  // 128 threads
    float cnt = (float)(gb[g + 1] - gb[g]);
    float v = (pooled[g * HD + c] * stats3[256 + c] + cnt * stats3[384 + c]) * fcw[c];
#pragma unroll
    for (int o = 32; o > 0; o >>= 1) v += __shfl_xor(v, o);
    if ((c & 63) == 0) red[c >> 6] = v;
    __syncthreads();
    if (c == 0) {
        float s = red[0] + red[1] + fcb[0];
        out[g] = 1.0f / (1.0f + expf(-s));
    }
}

extern "C" void kernel_launch(void* const* d_in, const int* in_sizes, int n_in,
                              void* d_out, int out_size, void* d_ws, size_t ws_size,
                              hipStream_t stream) {
    const float* x     = (const float*)d_in[0];
    const int*   ei    = (const int*)d_in[1];
    const int*   src   = ei;
    const int*   dst   = ei + NE;
    const int*   batch = (const int*)d_in[3];
    const float* Wl    = (const float*)d_in[4];
    const float* bl    = (const float*)d_in[5];
    const float* Wr    = (const float*)d_in[6];
    const float* gamma = (const float*)d_in[7];
    const float* beta  = (const float*)d_in[8];
    const float* fcw   = (const float*)d_in[9];
    const float* fcb   = (const float*)d_in[10];
    float* out = (float*)d_out;

    f16* hf0  = (f16*)d_ws;                       // [NN][128] fp16 (x converted)
    f16* hfA  = hf0 + (size_t)NN * HD;
    f16* hfB  = hfA + (size_t)NN * HD;
    f16* aggf = hfB + (size_t)NN * HD;
    f16* Wh   = aggf + (size_t)NN * HD;           // [128][256] fp16
    float* bias2    = (float*)(Wh + 128 * 256);   // 128
    float* statsAll = bias2 + HD;                 // 4*SB
    float* pooled   = statsAll + 4 * SB;          // NG*HD
    int* rowptr  = (int*)(pooled + NG * HD);      // NN+1
    int* perm    = rowptr + NN + 1;               // NE
    unsigned* staging = (unsigned*)(perm + NE);   // NE
    int* bcnt    = (int*)(staging + NE);          // NB
    int* bbase   = bcnt + NB;                     // NB+1
    int* bcur    = bbase + NB + 1;                // NB
    int* gb      = bcur + NB;                     // NG+1

    hipMemsetAsync(bcnt, 0, NB * sizeof(int), stream);
    hipMemsetAsync(pooled, 0, NG * HD * sizeof(float), stream);
    hipMemsetAsync(statsAll, 0, 4 * SB * sizeof(float), stream);

    buckcnt_kernel<<<(NE + EPB - 1) / EPB, 256, 0, stream>>>(dst, bcnt);
    buckscan_kernel<<<1, 256, 0, stream>>>(bcnt, bbase, bcur);
    buckscat_kernel<<<(NE + EPB - 1) / EPB, 256, 0, stream>>>(src, dst, bcur, staging);
    buckbuild_kernel<<<NB, 256, 0, stream>>>(staging, bbase, rowptr, perm);
    bounds_kernel<<<(NN + 255) / 256, 256, 0, stream>>>(batch, gb);
    statsinit_kernel<<<1, 128, 0, stream>>>(statsAll);
    cvt_kernel<<<(NN * 16 + 255) / 256, 256, 0, stream>>>(x, hf0);

    const f16* hin = hf0;
    f16* houts[3] = {hfA, hfB, hfA};
    for (int l = 0; l < NL; ++l) {
        float* stP = statsAll + l * SB;
        float* stN = statsAll + (l + 1) * SB;
        wprep_kernel<<<128, 256, 0, stream>>>(Wl + l * HD * HD, Wr + l * HD * HD,
                                              bl + l * HD, stP, Wh, bias2);
        gather_kernel<<<(NN * 16 + 255) / 256, 256, 0, stream>>>(hin, rowptr, perm, stP, aggf);
        mfma_gemm<<<(NN + 63) / 64, 256, 0, stream>>>(aggf, hin, Wh, bias2, houts[l], stN);
        bnprep_kernel<<<1, 128, 0, stream>>>(stN, gamma + l * HD, beta + l * HD);
        hin = houts[l];
    }
    pool2_kernel<<<NG * 8, 256, 0, stream>>>(hfA, gb, pooled);
    head_kernel<<<NG, 128, 0, stream>>>(pooled, gb, statsAll + 3 * SB, fcw, fcb, out);
}